// Round 2
// baseline (2138.809 us; speedup 1.0000x reference)
//
#include <hip/hip_runtime.h>
#include <math.h>

// Problem constants
#define DMODEL 256
#define NHEADS 8
#define NLAY 6
#define DFF 1024
#define DHEAD 32
#define NB 2
#define STOT 21760
#define MTOT (NB * STOT)   // 43520 = 128 * 340

typedef unsigned short u16;
typedef __attribute__((ext_vector_type(8))) short short8;
typedef __attribute__((ext_vector_type(4))) float floatx4;
typedef __attribute__((ext_vector_type(2))) float float2v;

__device__ __forceinline__ float bf2f(u16 h) {
    unsigned int u = ((unsigned int)h) << 16;
    return __uint_as_float(u);
}
__device__ __forceinline__ u16 f2bf(float f) {
    unsigned int u = __float_as_uint(f);
    u = u + 0x7fffu + ((u >> 16) & 1u);   // RNE
    return (u16)(u >> 16);
}

// packed dual-FMA: acc = a * b + acc (2 f32 lanes per instruction)
__device__ __forceinline__ void pkfma(float2v& acc, float2v a, float2v b) {
    asm("v_pk_fma_f32 %0, %1, %2, %0" : "+v"(acc) : "v"(a), "v"(b));
}
// packed bf16 pair (one uint) -> packed f32 pair
__device__ __forceinline__ float2v unpk(unsigned int u) {
    float2v r;
    r.x = __uint_as_float(u << 16);
    r.y = __uint_as_float(u & 0xffff0000u);
    return r;
}

// ---------------------------------------------------------------------------
// Concatenated bias [NLAY][384] = boff[i] (256) || battn[i] (128)
// ---------------------------------------------------------------------------
__global__ __launch_bounds__(256)
void biascat_kernel(const float* __restrict__ boff, const float* __restrict__ battn,
                    float* __restrict__ bias384)
{
    const int t = blockIdx.x * 256 + threadIdx.x;
    if (t >= NLAY * 384) return;
    const int i = t / 384, c = t - i * 384;
    bias384[t] = (c < 256) ? boff[i * 256 + c] : battn[i * 128 + (c - 256)];
}

// ---------------------------------------------------------------------------
// Weight transpose + bf16 cast: W[K,N] f32 -> Wt[N,K] bf16.
// ---------------------------------------------------------------------------
__global__ __launch_bounds__(256)
void wtrans_kernel(const float* __restrict__ W, u16* __restrict__ Wt,
                   const int K, const int N, const long wstride, const long ostride)
{
    __shared__ float ts[32][33];
    W  += blockIdx.z * wstride;
    Wt += blockIdx.z * ostride;
    const int n0 = blockIdx.x * 32;
    const int k0 = blockIdx.y * 32;
    const int t = threadIdx.x;
    const int nl = t & 31, kl = t >> 5;        // kl 0..7
#pragma unroll
    for (int p = 0; p < 4; ++p) {
        const int k = kl + p * 8;
        ts[k][nl] = W[(long)(k0 + k) * N + n0 + nl];
    }
    __syncthreads();
    const int c = t & 31, r0 = t >> 5;
#pragma unroll
    for (int p = 0; p < 4; ++p) {
        const int r = r0 + p * 8;
        Wt[(long)(n0 + r) * K + k0 + c] = f2bf(ts[c][r]);
    }
}

// ---------------------------------------------------------------------------
// Flatten: src[b,d,y,x] -> out f32, outb bf16, posb bf16, qb = bf16(src+pos+le)
// ---------------------------------------------------------------------------
__global__ __launch_bounds__(256)
void flatten_kernel(const float* __restrict__ src, const float* __restrict__ pos,
                    const float* __restrict__ le_row,
                    float* __restrict__ out, u16* __restrict__ outb,
                    u16* __restrict__ posb, u16* __restrict__ qb,
                    int HW, int start)
{
    __shared__ float ts[32][33];
    __shared__ float tp[32][33];
    const int b   = blockIdx.z;
    const int d0  = blockIdx.y * 32;
    const int hw0 = blockIdx.x * 32;
    const int t   = threadIdx.x;
    const int hwl = t & 31;
    const int dl  = t >> 5;
#pragma unroll
    for (int p = 0; p < 4; ++p) {
        const int dd = dl + p * 8;
        const int d  = d0 + dd;
        const long idx = ((long)(b * DMODEL + d)) * HW + hw0 + hwl;
        ts[dd][hwl] = src[idx];
        tp[dd][hwl] = pos[idx] + le_row[d];
    }
    __syncthreads();
    const int dl2  = t & 31;
    const int hwl2 = t >> 5;
#pragma unroll
    for (int p = 0; p < 4; ++p) {
        const int hh  = hwl2 + p * 8;
        const int tok = start + hw0 + hh;
        const long o  = ((long)(b * STOT + tok)) * DMODEL + d0 + dl2;
        const float v = ts[dl2][hh];
        const float pp = tp[dl2][hh];
        out[o]  = v;
        outb[o] = f2bf(v);
        posb[o] = f2bf(pp);
        qb[o]   = f2bf(v + pp);
    }
}

// ---------------------------------------------------------------------------
// bf16 MFMA GEMM: Cb[M,N]bf16 = A[M,K]bf16 @ Bt[N,K]bf16^T + bias (relu opt)
// ---------------------------------------------------------------------------
__global__ __launch_bounds__(256)
void mfma_gemm(const u16* __restrict__ A, const u16* __restrict__ Bt,
               const int ldb, const float* __restrict__ bias,
               u16* __restrict__ Cb, const int ldc, u16* __restrict__ Cb2,
               const int K, const int relu)
{
    __shared__ u16 As[128 * 40];
    __shared__ u16 Bs[128 * 40];
    const int tid  = threadIdx.x;
    const int wv   = tid >> 6;
    const int lane = tid & 63;
    const int m0 = blockIdx.y * 128;
    const int n0 = blockIdx.x * 128;
    const int wm = (wv & 1) * 64;
    const int wn = (wv >> 1) * 64;
    const int q   = lane >> 4;
    const int c16 = lane & 15;

    const int srow = tid >> 2;        // 0..63
    const int scol = (tid & 3) * 8;   // 0,8,16,24

    floatx4 acc[4][4];
#pragma unroll
    for (int i = 0; i < 4; ++i)
#pragma unroll
        for (int j = 0; j < 4; ++j)
            acc[i][j] = (floatx4){0.f, 0.f, 0.f, 0.f};

    union Frag { short8 v; uint2 u[2]; };

    for (int k0 = 0; k0 < K; k0 += 32) {
#pragma unroll
        for (int it = 0; it < 2; ++it) {
            const int r = srow + it * 64;
            const uint4 va = *(const uint4*)(A + (long)(m0 + r) * K + k0 + scol);
            uint2 lo, hi;
            lo.x = va.x; lo.y = va.y; hi.x = va.z; hi.y = va.w;
            *(uint2*)&As[r * 40 + scol]     = lo;
            *(uint2*)&As[r * 40 + scol + 4] = hi;
            const uint4 vb = *(const uint4*)(Bt + (long)(n0 + r) * ldb + k0 + scol);
            lo.x = vb.x; lo.y = vb.y; hi.x = vb.z; hi.y = vb.w;
            *(uint2*)&Bs[r * 40 + scol]     = lo;
            *(uint2*)&Bs[r * 40 + scol + 4] = hi;
        }
        __syncthreads();

        short8 af[4], bf[4];
#pragma unroll
        for (int i = 0; i < 4; ++i) {
            Frag fa;
            const int ao = (wm + i * 16 + c16) * 40 + q * 8;
            fa.u[0] = *(const uint2*)&As[ao];
            fa.u[1] = *(const uint2*)&As[ao + 4];
            af[i] = fa.v;
            Frag fb;
            const int bo = (wn + i * 16 + c16) * 40 + q * 8;
            fb.u[0] = *(const uint2*)&Bs[bo];
            fb.u[1] = *(const uint2*)&Bs[bo + 4];
            bf[i] = fb.v;
        }
#pragma unroll
        for (int i = 0; i < 4; ++i)
#pragma unroll
            for (int j = 0; j < 4; ++j)
                acc[i][j] = __builtin_amdgcn_mfma_f32_16x16x32_bf16(
                    af[i], bf[j], acc[i][j], 0, 0, 0);
        __syncthreads();
    }

    // output selection (block-uniform)
    u16* cb  = Cb;
    int ldcb = ldc, csub = 0;
    if (Cb2 && n0 >= 256) { cb = Cb2; ldcb = 128; csub = 256; }

#pragma unroll
    for (int i = 0; i < 4; ++i) {
#pragma unroll
        for (int j = 0; j < 4; ++j) {
            const int col = n0 + wn + j * 16 + c16;
            const float bv = bias ? bias[col] : 0.f;
#pragma unroll
            for (int r = 0; r < 4; ++r) {
                const int row = m0 + wm + i * 16 + q * 4 + r;
                float v = acc[i][j][r] + bv;
                if (relu) v = fmaxf(v, 0.f);
                cb[(long)row * ldcb + col - csub] = f2bf(v);
            }
        }
    }
}

// ---------------------------------------------------------------------------
// Deformable sampling, point-parallel decomposition.
// Wave = one token. Lane (h = l>>3, q = l&7) owns points {q, q+8} of head h
// and gathers ALL 32 channels of each corner (4 x dwordx4 = 64B contiguous).
// Per-head softmax via 3-step shfl_xor over the 8 lanes. Channel reduction
// (8 lanes x 32 ch -> 4 ch/lane) via in-wave LDS exchange (no barrier).
// v_pk_fma_f32 does 2 channels per instruction.
// ---------------------------------------------------------------------------
__device__ __forceinline__ void point_corners(
    float refx, float refy, unsigned int o2, float aP,
    int k, unsigned int base, float w[4], unsigned int o[4])
{
    const int lw = 128 >> k;
    const float flw = (float)lw;
    const float x = refx * flw - 0.5f + bf2f((u16)(o2 & 0xffffu));
    const float y = refy * flw - 0.5f + bf2f((u16)(o2 >> 16));
    const float x0f = floorf(x), y0f = floorf(y);
    const float lx = x - x0f, ly = y - y0f;
    const int x0 = (int)x0f, y0 = (int)y0f;
    const float wx0 = ((unsigned int)x0 < (unsigned int)lw) ? (1.f - lx) : 0.f;
    const float wx1 = ((unsigned int)(x0 + 1) < (unsigned int)lw) ? lx : 0.f;
    const float wy0 = ((unsigned int)y0 < (unsigned int)lw) ? (aP * (1.f - ly)) : 0.f;
    const float wy1 = ((unsigned int)(y0 + 1) < (unsigned int)lw) ? (aP * ly) : 0.f;
    // byte offsets: token stride 512B; row stride lw*512 = 1<<(16-k)
    const unsigned int xc0 = (unsigned int)(x0 & (lw - 1)) << 9;
    const unsigned int xc1 = (unsigned int)((x0 + 1) & (lw - 1)) << 9;
    const unsigned int r0 = (unsigned int)(y0 & (lw - 1)) << (16 - k);
    const unsigned int r1 = (unsigned int)((y0 + 1) & (lw - 1)) << (16 - k);
    w[0] = wy0 * wx0; o[0] = base + r0 + xc0;
    w[1] = wy0 * wx1; o[1] = base + r0 + xc1;
    w[2] = wy1 * wx0; o[2] = base + r1 + xc0;
    w[3] = wy1 * wx1; o[3] = base + r1 + xc1;
}

__device__ __forceinline__ void corner_acc(const char* __restrict__ vp,
                                           unsigned int o, float w,
                                           float2v acc[16])
{
    const uint4 d0 = *(const uint4*)(vp + o);
    const uint4 d1 = *(const uint4*)(vp + o + 16);
    const uint4 d2 = *(const uint4*)(vp + o + 32);
    const uint4 d3 = *(const uint4*)(vp + o + 48);
    float2v w2; w2.x = w; w2.y = w;
    pkfma(acc[0],  w2, unpk(d0.x));
    pkfma(acc[1],  w2, unpk(d0.y));
    pkfma(acc[2],  w2, unpk(d0.z));
    pkfma(acc[3],  w2, unpk(d0.w));
    pkfma(acc[4],  w2, unpk(d1.x));
    pkfma(acc[5],  w2, unpk(d1.y));
    pkfma(acc[6],  w2, unpk(d1.z));
    pkfma(acc[7],  w2, unpk(d1.w));
    pkfma(acc[8],  w2, unpk(d2.x));
    pkfma(acc[9],  w2, unpk(d2.y));
    pkfma(acc[10], w2, unpk(d2.z));
    pkfma(acc[11], w2, unpk(d2.w));
    pkfma(acc[12], w2, unpk(d3.x));
    pkfma(acc[13], w2, unpk(d3.y));
    pkfma(acc[14], w2, unpk(d3.z));
    pkfma(acc[15], w2, unpk(d3.w));
}

__global__ __launch_bounds__(256)
void sample_kernel(const u16* __restrict__ value, const u16* __restrict__ offb,
                   const u16* __restrict__ logit, u16* __restrict__ sb)
{
    __shared__ float red[4][64][33];

    const int t  = threadIdx.x;
    const int wv = t >> 6;                 // token slot within block
    const int l  = t & 63;
    const int h  = l >> 3;                 // head 0..7
    const int q  = l & 7;                  // point-pair: points q and q+8
    const int blk = blockIdx.x * 4 + wv;   // global token
    const int b = blk / STOT;
    const int s = blk - b * STOT;

    float refx, refy;
    if (s < 16384) {
        const int yy = s >> 7, xx = s & 127;
        refx = (xx + 0.5f) * (1.f / 128.f); refy = (yy + 0.5f) * (1.f / 128.f);
    } else if (s < 20480) {
        const int sl = s - 16384; const int yy = sl >> 6, xx = sl & 63;
        refx = (xx + 0.5f) * (1.f / 64.f);  refy = (yy + 0.5f) * (1.f / 64.f);
    } else if (s < 21504) {
        const int sl = s - 20480; const int yy = sl >> 5, xx = sl & 31;
        refx = (xx + 0.5f) * (1.f / 32.f);  refy = (yy + 0.5f) * (1.f / 32.f);
    } else {
        const int sl = s - 21504; const int yy = sl >> 4, xx = sl & 15;
        refx = (xx + 0.5f) * (1.f / 16.f);  refy = (yy + 0.5f) * (1.f / 16.f);
    }

    // ---- loads: this lane's 2 offset pairs + 2 logits ----
    const unsigned int* offp = (const unsigned int*)(offb + (long)blk * 256 + h * 32);
    const unsigned int o2_0 = offp[q];
    const unsigned int o2_1 = offp[q + 8];
    const u16* lp = logit + (long)blk * 128 + h * 16;
    const float l0 = bf2f(lp[q]);
    const float l1 = bf2f(lp[q + 8]);

    // ---- softmax across the head's 8 lanes (16 logits) ----
    float m = fmaxf(l0, l1);
    m = fmaxf(m, __shfl_xor(m, 1));
    m = fmaxf(m, __shfl_xor(m, 2));
    m = fmaxf(m, __shfl_xor(m, 4));
    const float e0 = __expf(l0 - m);
    const float e1 = __expf(l1 - m);
    float se = e0 + e1;
    se += __shfl_xor(se, 1);
    se += __shfl_xor(se, 2);
    se += __shfl_xor(se, 4);
    const float inv = 1.f / se;
    const float aP0 = e0 * inv;
    const float aP1 = e1 * inv;

    // ---- per-point level constants (k0 in {0,1}, k1 in {2,3}) ----
    const int k0 = q >> 2;
    const int k1 = k0 + 2;
    const unsigned int LS0 = k0 ? 16384u : 0u;
    const unsigned int LS1 = k0 ? 21504u : 20480u;
    const unsigned int tb = (unsigned int)(b * STOT);
    const unsigned int hb64 = (unsigned int)(h * 64);
    const unsigned int base0 = (tb + LS0) * 512u + hb64;
    const unsigned int base1 = (tb + LS1) * 512u + hb64;

    float w0[4], w1[4];
    unsigned int oo0[4], oo1[4];
    point_corners(refx, refy, o2_0, aP0, k0, base0, w0, oo0);
    point_corners(refx, refy, o2_1, aP1, k1, base1, w1, oo1);

    float2v acc[16];
#pragma unroll
    for (int n = 0; n < 16; ++n) { acc[n].x = 0.f; acc[n].y = 0.f; }

    const char* vp = (const char*)value;
#pragma unroll
    for (int c = 0; c < 4; ++c) corner_acc(vp, oo0[c], w0[c], acc);
#pragma unroll
    for (int c = 0; c < 4; ++c) corner_acc(vp, oo1[c], w1[c], acc);

    // ---- in-wave channel reduction: 8 lanes x 32 ch -> 4 ch per lane ----
    float* myrow = red[wv][l];
#pragma unroll
    for (int c = 0; c < 8; ++c) {
        float4 v4;
        v4.x = acc[2 * c].x;     v4.y = acc[2 * c].y;
        v4.z = acc[2 * c + 1].x; v4.w = acc[2 * c + 1].y;
        *(float4*)(myrow + c * 4) = v4;
    }
    __builtin_amdgcn_wave_barrier();
    const float* hrow = red[wv][h * 8];
    float4 sum; sum.x = 0.f; sum.y = 0.f; sum.z = 0.f; sum.w = 0.f;
#pragma unroll
    for (int j = 0; j < 8; ++j) {
        const float4 v = *(const float4*)(hrow + j * 33 + q * 4);
        sum.x += v.x; sum.y += v.y; sum.z += v.z; sum.w += v.w;
    }

    ushort4 r;
    r.x = f2bf(sum.x); r.y = f2bf(sum.y); r.z = f2bf(sum.z); r.w = f2bf(sum.w);
    *(ushort4*)(sb + (long)blk * DMODEL + h * 32 + q * 4) = r;
}

// ---------------------------------------------------------------------------
// out = LayerNorm(out + delta_bf16); writes f32 residual + bf16 outb.
// If qb != null: also writes qb = bf16(LNout + posb) for next layer's q-GEMM.
// ---------------------------------------------------------------------------
__global__ __launch_bounds__(256)
void ln_kernel(float* __restrict__ out, u16* __restrict__ outb,
               u16* __restrict__ qb, const u16* __restrict__ posb,
               const u16* __restrict__ db,
               const float* __restrict__ gamma, const float* __restrict__ beta)
{
    const int wave = threadIdx.x >> 6;
    const int lane = threadIdx.x & 63;
    const long tok = (long)blockIdx.x * 4 + wave;
    float* op = out + tok * DMODEL + lane * 4;
    const float4 xo = *(const float4*)op;
    const ushort4 d4 = *(const ushort4*)(db + tok * DMODEL + lane * 4);
    float x[4] = {xo.x + bf2f(d4.x), xo.y + bf2f(d4.y),
                  xo.z + bf2f(d4.z), xo.w + bf2f(d4.w)};

    float sum = x[0] + x[1] + x[2] + x[3];
#pragma unroll
    for (int o = 32; o >= 1; o >>= 1) sum += __shfl_xor(sum, o);
    const float mean = sum * (1.f / 256.f);

    float vs = 0.f;
#pragma unroll
    for (int i = 0; i < 4; ++i) { const float d2 = x[i] - mean; vs += d2 * d2; }
#pragma unroll
    for (int o = 32; o >= 1; o >>= 1) vs += __shfl_xor(vs, o);
    const float rstd = rsqrtf(vs * (1.f / 256.f) + 1e-5f);

    const float4 g  = *(const float4*)(gamma + lane * 4);
    const float4 be = *(const float4*)(beta + lane * 4);
    float r[4];
    r[0] = (x[0] - mean) * rstd * g.x + be.x;
    r[1] = (x[1] - mean) * rstd * g.y + be.y;
    r[2] = (x[2] - mean) * rstd * g.z + be.z;
    r[3] = (x[3] - mean) * rstd * g.w + be.w;
    float4 rf; rf.x = r[0]; rf.y = r[1]; rf.z = r[2]; rf.w = r[3];
    *(float4*)op = rf;
    ushort4 rb;
    rb.x = f2bf(r[0]); rb.y = f2bf(r[1]); rb.z = f2bf(r[2]); rb.w = f2bf(r[3]);
    *(ushort4*)(outb + tok * DMODEL + lane * 4) = rb;
    if (qb) {
        const ushort4 p4 = *(const ushort4*)(posb + tok * DMODEL + lane * 4);
        ushort4 qv;
        qv.x = f2bf(r[0] + bf2f(p4.x));
        qv.y = f2bf(r[1] + bf2f(p4.y));
        qv.z = f2bf(r[2] + bf2f(p4.z));
        qv.w = f2bf(r[3] + bf2f(p4.w));
        *(ushort4*)(qb + tok * DMODEL + lane * 4) = qv;
    }
}

// ---------------------------------------------------------------------------
extern "C" void kernel_launch(void* const* d_in, const int* in_sizes, int n_in,
                              void* d_out, int out_size, void* d_ws, size_t ws_size,
                              hipStream_t stream)
{
    const float* src[4] = {(const float*)d_in[0], (const float*)d_in[2],
                           (const float*)d_in[4], (const float*)d_in[6]};
    const float* pos[4] = {(const float*)d_in[1], (const float*)d_in[3],
                           (const float*)d_in[5], (const float*)d_in[7]};
    const float* level_embed = (const float*)d_in[8];
    const float* Woff  = (const float*)d_in[9];
    const float* boff  = (const float*)d_in[10];
    const float* Wattn = (const float*)d_in[11];
    const float* battn = (const float*)d_in[12];
    const float* Wval  = (const float*)d_in[13];
    const float* bval  = (const float*)d_in[14];
    const float* Wout  = (const float*)d_in[15];
    const float* bout  = (const float*)d_in[16];
    const float* ln1s  = (const float*)d_in[17];
    const float* ln1b  = (const float*)d_in[18];
    const float* W1    = (const float*)d_in[19];
    const float* b1    = (const float*)d_in[20];
    const float* W2    = (const float*)d_in[21];
    const float* b2    = (const float*)d_in[22];
    const float* ln2s  = (const float*)d_in[23];
    const float* ln2b  = (const float*)d_in[24];

    float* out = (float*)d_out;                       // residual stream f32
    const long MD = (long)MTOT * DMODEL;              // 11,141,120

    // workspace layout (~187 MB)
    u16* outb = (u16*)d_ws;          // [M,256] LN output bf16
    u16* posb = outb + MD;           // [M,256] pos_flat bf16
    u16* qb   = posb + MD;           // [M,256] q = out+pos bf16
    u16* db   = qb + MD;             // [M,256] delta bf16 (attn_out / ff_out)
    u16* vb   = db + MD;             // [M,256] value bf16      (hb region start)
    u16* offb = vb + MD;             // [M,256] offsets bf16
    u16* awb  = offb + MD;           // [M,128] attn logits bf16
    u16* sb   = awb + MD / 2;        // [M,256] sampled bf16
    u16* hb   = vb;                  // [M,1024] FF hidden (aliases vb..sb+pad)
    u16* wts  = vb + 4 * MD;         // bf16 transposed weights
    u16* Wvalt = wts;
    u16* Wofat = Wvalt + 6L * 256 * 256;   // [384,256] per layer: Woff^T||Wattn^T
    u16* Woutt = Wofat + 6L * 384 * 256;
    u16* W1t   = Woutt + 6L * 256 * 256;
    u16* W2t   = W1t   + 6L * 1024 * 256;
    float* bias384 = (float*)(W2t + 6L * 1024 * 256);  // [NLAY][384]

    // ---- weight prep (every call; ~9 MB) ----
    biascat_kernel<<<9, 256, 0, stream>>>(boff, battn, bias384);
    wtrans_kernel<<<dim3(8, 8, 6),  256, 0, stream>>>(Wval,  Wvalt, 256, 256,
                                                      65536, 65536);
    wtrans_kernel<<<dim3(8, 8, 6),  256, 0, stream>>>(Woff,  Wofat, 256, 256,
                                                      65536, 98304);
    wtrans_kernel<<<dim3(4, 8, 6),  256, 0, stream>>>(Wattn, Wofat + 256 * 256,
                                                      256, 128, 32768, 98304);
    wtrans_kernel<<<dim3(8, 8, 6),  256, 0, stream>>>(Wout,  Woutt, 256, 256,
                                                      65536, 65536);
    wtrans_kernel<<<dim3(32, 8, 6), 256, 0, stream>>>(W1,    W1t, 256, 1024,
                                                      262144, 262144);
    wtrans_kernel<<<dim3(8, 32, 6), 256, 0, stream>>>(W2,    W2t, 1024, 256,
                                                      262144, 262144);

    // ---- flatten ----
    {
        const int HW[4] = {16384, 4096, 1024, 256};
        const int ST[4] = {0, 16384, 20480, 21504};
        for (int l = 0; l < 4; ++l) {
            dim3 g(HW[l] / 32, DMODEL / 32, NB);
            flatten_kernel<<<g, 256, 0, stream>>>(src[l], pos[l],
                                                  level_embed + l * DMODEL,
                                                  out, outb, posb, qb, HW[l], ST[l]);
        }
    }

    const dim3 g2(2, MTOT / 128);   // N=256
    const dim3 g3(3, MTOT / 128);   // N=384 (merged off||attn)
    const dim3 g8(8, MTOT / 128);   // N=1024 (FF1)

    for (int i = 0; i < NLAY; ++i) {
        const u16* Wv  = Wvalt + (long)i * 256 * 256;
        const u16* Wqa = Wofat + (long)i * 384 * 256;
        const u16* Wou = Woutt + (long)i * 256 * 256;
        const u16* W1i = W1t   + (long)i * 1024 * 256;
        const u16* W2i = W2t   + (long)i * 256 * 1024;
        const float* bv  = bval + (long)i * 256;
        const float* bqa = bias384 + (long)i * 384;
        const float* bou = bout + (long)i * 256;
        const float* b1i = b1   + (long)i * DFF;
        const float* b2i = b2   + (long)i * 256;

        // value = out @ Wval + bval -> vb bf16
        mfma_gemm<<<g2, 256, 0, stream>>>(outb, Wv, 256, bv,
                                          vb, 256, nullptr, 256, 0);
        // [off | attn logits] = q @ [Woff|Wattn] -> offb bf16, awb bf16
        mfma_gemm<<<g3, 256, 0, stream>>>(qb, Wqa, 256, bqa,
                                          offb, 256, awb, 256, 0);
        // sampling with fused softmax (reads logits directly)
        sample_kernel<<<MTOT / 4, 256, 0, stream>>>(vb, offb, awb, sb);
        // attn_out = s @ Wout + bout -> db bf16
        mfma_gemm<<<g2, 256, 0, stream>>>(sb, Wou, 256, bou,
                                          db, 256, nullptr, 256, 0);
        ln_kernel<<<MTOT / 4, 256, 0, stream>>>(out, outb, nullptr, nullptr, db,
                                                ln1s + (long)i * 256,
                                                ln1b + (long)i * 256);
        // FF: h = relu(out @ W1 + b1) -> hb bf16 [M,1024]
        mfma_gemm<<<g8, 256, 0, stream>>>(outb, W1i, 256, b1i,
                                          hb, 1024, nullptr, 256, 1);
        // ff_out = h @ W2 + b2 -> db bf16
        mfma_gemm<<<g2, 256, 0, stream>>>(hb, W2i, 1024, b2i,
                                          db, 256, nullptr, 1024, 0);
        ln_kernel<<<MTOT / 4, 256, 0, stream>>>(out, outb, qb, posb, db,
                                                ln2s + (long)i * 256,
                                                ln2b + (long)i * 256);
    }
}

// Round 3
// 2129.008 us; speedup vs baseline: 1.0046x; 1.0046x over previous
//
#include <hip/hip_runtime.h>
#include <math.h>

// Problem constants
#define DMODEL 256
#define NHEADS 8
#define NLAY 6
#define DFF 1024
#define DHEAD 32
#define NB 2
#define STOT 21760
#define MTOT (NB * STOT)   // 43520 = 128 * 340

typedef unsigned short u16;
typedef __attribute__((ext_vector_type(8))) short short8;
typedef __attribute__((ext_vector_type(4))) float floatx4;
typedef __attribute__((ext_vector_type(2))) float float2v;

__device__ __forceinline__ float bf2f(u16 h) {
    unsigned int u = ((unsigned int)h) << 16;
    return __uint_as_float(u);
}
__device__ __forceinline__ u16 f2bf(float f) {
    unsigned int u = __float_as_uint(f);
    u = u + 0x7fffu + ((u >> 16) & 1u);   // RNE
    return (u16)(u >> 16);
}

// packed dual-FMA: acc = a * b + acc (2 f32 lanes per instruction)
__device__ __forceinline__ void pkfma(float2v& acc, float2v a, float2v b) {
    asm("v_pk_fma_f32 %0, %1, %2, %0" : "+v"(acc) : "v"(a), "v"(b));
}
// packed bf16 pair (one uint) -> packed f32 pair
__device__ __forceinline__ float2v unpk(unsigned int u) {
    float2v r;
    r.x = __uint_as_float(u << 16);
    r.y = __uint_as_float(u & 0xffff0000u);
    return r;
}

// ---------------------------------------------------------------------------
// Concatenated bias [NLAY][384] = boff[i] (256) || battn[i] (128)
// ---------------------------------------------------------------------------
__global__ __launch_bounds__(256)
void biascat_kernel(const float* __restrict__ boff, const float* __restrict__ battn,
                    float* __restrict__ bias384)
{
    const int t = blockIdx.x * 256 + threadIdx.x;
    if (t >= NLAY * 384) return;
    const int i = t / 384, c = t - i * 384;
    bias384[t] = (c < 256) ? boff[i * 256 + c] : battn[i * 128 + (c - 256)];
}

// ---------------------------------------------------------------------------
// Weight transpose + bf16 cast: W[K,N] f32 -> Wt[N,K] bf16.
// ---------------------------------------------------------------------------
__global__ __launch_bounds__(256)
void wtrans_kernel(const float* __restrict__ W, u16* __restrict__ Wt,
                   const int K, const int N, const long wstride, const long ostride)
{
    __shared__ float ts[32][33];
    W  += blockIdx.z * wstride;
    Wt += blockIdx.z * ostride;
    const int n0 = blockIdx.x * 32;
    const int k0 = blockIdx.y * 32;
    const int t = threadIdx.x;
    const int nl = t & 31, kl = t >> 5;        // kl 0..7
#pragma unroll
    for (int p = 0; p < 4; ++p) {
        const int k = kl + p * 8;
        ts[k][nl] = W[(long)(k0 + k) * N + n0 + nl];
    }
    __syncthreads();
    const int c = t & 31, r0 = t >> 5;
#pragma unroll
    for (int p = 0; p < 4; ++p) {
        const int r = r0 + p * 8;
        Wt[(long)(n0 + r) * K + k0 + c] = f2bf(ts[c][r]);
    }
}

// ---------------------------------------------------------------------------
// Flatten: src[b,d,y,x] -> out f32, outb bf16, posb bf16, qb = bf16(src+pos+le)
// ---------------------------------------------------------------------------
__global__ __launch_bounds__(256)
void flatten_kernel(const float* __restrict__ src, const float* __restrict__ pos,
                    const float* __restrict__ le_row,
                    float* __restrict__ out, u16* __restrict__ outb,
                    u16* __restrict__ posb, u16* __restrict__ qb,
                    int HW, int start)
{
    __shared__ float ts[32][33];
    __shared__ float tp[32][33];
    const int b   = blockIdx.z;
    const int d0  = blockIdx.y * 32;
    const int hw0 = blockIdx.x * 32;
    const int t   = threadIdx.x;
    const int hwl = t & 31;
    const int dl  = t >> 5;
#pragma unroll
    for (int p = 0; p < 4; ++p) {
        const int dd = dl + p * 8;
        const int d  = d0 + dd;
        const long idx = ((long)(b * DMODEL + d)) * HW + hw0 + hwl;
        ts[dd][hwl] = src[idx];
        tp[dd][hwl] = pos[idx] + le_row[d];
    }
    __syncthreads();
    const int dl2  = t & 31;
    const int hwl2 = t >> 5;
#pragma unroll
    for (int p = 0; p < 4; ++p) {
        const int hh  = hwl2 + p * 8;
        const int tok = start + hw0 + hh;
        const long o  = ((long)(b * STOT + tok)) * DMODEL + d0 + dl2;
        const float v = ts[dl2][hh];
        const float pp = tp[dl2][hh];
        out[o]  = v;
        outb[o] = f2bf(v);
        posb[o] = f2bf(pp);
        qb[o]   = f2bf(v + pp);
    }
}

// ---------------------------------------------------------------------------
// bf16 MFMA GEMM: Cb[M,N]bf16 = A[M,K]bf16 @ Bt[N,K]bf16^T + bias (relu opt)
// ---------------------------------------------------------------------------
__global__ __launch_bounds__(256)
void mfma_gemm(const u16* __restrict__ A, const u16* __restrict__ Bt,
               const int ldb, const float* __restrict__ bias,
               u16* __restrict__ Cb, const int ldc, u16* __restrict__ Cb2,
               const int K, const int relu)
{
    __shared__ u16 As[128 * 40];
    __shared__ u16 Bs[128 * 40];
    const int tid  = threadIdx.x;
    const int wv   = tid >> 6;
    const int lane = tid & 63;
    const int m0 = blockIdx.y * 128;
    const int n0 = blockIdx.x * 128;
    const int wm = (wv & 1) * 64;
    const int wn = (wv >> 1) * 64;
    const int q   = lane >> 4;
    const int c16 = lane & 15;

    const int srow = tid >> 2;        // 0..63
    const int scol = (tid & 3) * 8;   // 0,8,16,24

    floatx4 acc[4][4];
#pragma unroll
    for (int i = 0; i < 4; ++i)
#pragma unroll
        for (int j = 0; j < 4; ++j)
            acc[i][j] = (floatx4){0.f, 0.f, 0.f, 0.f};

    union Frag { short8 v; uint2 u[2]; };

    for (int k0 = 0; k0 < K; k0 += 32) {
#pragma unroll
        for (int it = 0; it < 2; ++it) {
            const int r = srow + it * 64;
            const uint4 va = *(const uint4*)(A + (long)(m0 + r) * K + k0 + scol);
            uint2 lo, hi;
            lo.x = va.x; lo.y = va.y; hi.x = va.z; hi.y = va.w;
            *(uint2*)&As[r * 40 + scol]     = lo;
            *(uint2*)&As[r * 40 + scol + 4] = hi;
            const uint4 vb = *(const uint4*)(Bt + (long)(n0 + r) * ldb + k0 + scol);
            lo.x = vb.x; lo.y = vb.y; hi.x = vb.z; hi.y = vb.w;
            *(uint2*)&Bs[r * 40 + scol]     = lo;
            *(uint2*)&Bs[r * 40 + scol + 4] = hi;
        }
        __syncthreads();

        short8 af[4], bf[4];
#pragma unroll
        for (int i = 0; i < 4; ++i) {
            Frag fa;
            const int ao = (wm + i * 16 + c16) * 40 + q * 8;
            fa.u[0] = *(const uint2*)&As[ao];
            fa.u[1] = *(const uint2*)&As[ao + 4];
            af[i] = fa.v;
            Frag fb;
            const int bo = (wn + i * 16 + c16) * 40 + q * 8;
            fb.u[0] = *(const uint2*)&Bs[bo];
            fb.u[1] = *(const uint2*)&Bs[bo + 4];
            bf[i] = fb.v;
        }
#pragma unroll
        for (int i = 0; i < 4; ++i)
#pragma unroll
            for (int j = 0; j < 4; ++j)
                acc[i][j] = __builtin_amdgcn_mfma_f32_16x16x32_bf16(
                    af[i], bf[j], acc[i][j], 0, 0, 0);
        __syncthreads();
    }

    // output selection (block-uniform)
    u16* cb  = Cb;
    int ldcb = ldc, csub = 0;
    if (Cb2 && n0 >= 256) { cb = Cb2; ldcb = 128; csub = 256; }

#pragma unroll
    for (int i = 0; i < 4; ++i) {
#pragma unroll
        for (int j = 0; j < 4; ++j) {
            const int col = n0 + wn + j * 16 + c16;
            const float bv = bias ? bias[col] : 0.f;
#pragma unroll
            for (int r = 0; r < 4; ++r) {
                const int row = m0 + wm + i * 16 + q * 4 + r;
                float v = acc[i][j][r] + bv;
                if (relu) v = fmaxf(v, 0.f);
                cb[(long)row * ldcb + col - csub] = f2bf(v);
            }
        }
    }
}

// ---------------------------------------------------------------------------
// Deformable sampling, point-parallel, software-pipelined gathers.
// Wave = one token. Lane (h = l>>3, q = l&7) owns points {q, q+8} of head h,
// gathers all 32 channels of each of its 8 corners (4 x dwordx4 each).
// 4-corner-deep load pipeline (16 uint4 in flight), launch_bounds (256,4)
// to allow ~128 VGPRs. Channel reduction via in-wave shuffle reduce-scatter
// (no LDS, no barrier). Per-head softmax via 3-step shfl_xor.
// ---------------------------------------------------------------------------
__device__ __forceinline__ void point_corners(
    float refx, float refy, unsigned int o2, float aP,
    int k, unsigned int base, float* w, unsigned int* o)
{
    const int lw = 128 >> k;
    const float flw = (float)lw;
    const float x = refx * flw - 0.5f + bf2f((u16)(o2 & 0xffffu));
    const float y = refy * flw - 0.5f + bf2f((u16)(o2 >> 16));
    const float x0f = floorf(x), y0f = floorf(y);
    const float lx = x - x0f, ly = y - y0f;
    const int x0 = (int)x0f, y0 = (int)y0f;
    const float wx0 = ((unsigned int)x0 < (unsigned int)lw) ? (1.f - lx) : 0.f;
    const float wx1 = ((unsigned int)(x0 + 1) < (unsigned int)lw) ? lx : 0.f;
    const float wy0 = ((unsigned int)y0 < (unsigned int)lw) ? (aP * (1.f - ly)) : 0.f;
    const float wy1 = ((unsigned int)(y0 + 1) < (unsigned int)lw) ? (aP * ly) : 0.f;
    // byte offsets: token stride 512B; row stride lw*512 = 1<<(16-k)
    const unsigned int xc0 = (unsigned int)(x0 & (lw - 1)) << 9;
    const unsigned int xc1 = (unsigned int)((x0 + 1) & (lw - 1)) << 9;
    const unsigned int r0 = (unsigned int)(y0 & (lw - 1)) << (16 - k);
    const unsigned int r1 = (unsigned int)((y0 + 1) & (lw - 1)) << (16 - k);
    w[0] = wy0 * wx0; o[0] = base + r0 + xc0;
    w[1] = wy0 * wx1; o[1] = base + r0 + xc1;
    w[2] = wy1 * wx0; o[2] = base + r1 + xc0;
    w[3] = wy1 * wx1; o[3] = base + r1 + xc1;
}

#define LD_CORNER(D, off)                                   \
    D[0] = *(const uint4*)(vp + (off));                     \
    D[1] = *(const uint4*)(vp + (off) + 16);                \
    D[2] = *(const uint4*)(vp + (off) + 32);                \
    D[3] = *(const uint4*)(vp + (off) + 48);

#define FMA_CORNER(D, wgt)                                  \
    {                                                       \
        float2v w2; w2.x = (wgt); w2.y = (wgt);             \
        pkfma(acc[0],  w2, unpk(D[0].x));                   \
        pkfma(acc[1],  w2, unpk(D[0].y));                   \
        pkfma(acc[2],  w2, unpk(D[0].z));                   \
        pkfma(acc[3],  w2, unpk(D[0].w));                   \
        pkfma(acc[4],  w2, unpk(D[1].x));                   \
        pkfma(acc[5],  w2, unpk(D[1].y));                   \
        pkfma(acc[6],  w2, unpk(D[1].z));                   \
        pkfma(acc[7],  w2, unpk(D[1].w));                   \
        pkfma(acc[8],  w2, unpk(D[2].x));                   \
        pkfma(acc[9],  w2, unpk(D[2].y));                   \
        pkfma(acc[10], w2, unpk(D[2].z));                   \
        pkfma(acc[11], w2, unpk(D[2].w));                   \
        pkfma(acc[12], w2, unpk(D[3].x));                   \
        pkfma(acc[13], w2, unpk(D[3].y));                   \
        pkfma(acc[14], w2, unpk(D[3].z));                   \
        pkfma(acc[15], w2, unpk(D[3].w));                   \
    }

__global__ __launch_bounds__(256, 4)
void sample_kernel(const u16* __restrict__ value, const u16* __restrict__ offb,
                   const u16* __restrict__ logit, u16* __restrict__ sb)
{
    const int t  = threadIdx.x;
    const int wv = t >> 6;                 // token slot within block
    const int l  = t & 63;
    const int h  = l >> 3;                 // head 0..7
    const int q  = l & 7;                  // point-pair: points q and q+8
    const int blk = blockIdx.x * 4 + wv;   // global token
    const int b = blk / STOT;
    const int s = blk - b * STOT;

    float refx, refy;
    if (s < 16384) {
        const int yy = s >> 7, xx = s & 127;
        refx = (xx + 0.5f) * (1.f / 128.f); refy = (yy + 0.5f) * (1.f / 128.f);
    } else if (s < 20480) {
        const int sl = s - 16384; const int yy = sl >> 6, xx = sl & 63;
        refx = (xx + 0.5f) * (1.f / 64.f);  refy = (yy + 0.5f) * (1.f / 64.f);
    } else if (s < 21504) {
        const int sl = s - 20480; const int yy = sl >> 5, xx = sl & 31;
        refx = (xx + 0.5f) * (1.f / 32.f);  refy = (yy + 0.5f) * (1.f / 32.f);
    } else {
        const int sl = s - 21504; const int yy = sl >> 4, xx = sl & 15;
        refx = (xx + 0.5f) * (1.f / 16.f);  refy = (yy + 0.5f) * (1.f / 16.f);
    }

    // ---- this lane's 2 offset pairs + 2 logits ----
    const unsigned int* offp = (const unsigned int*)(offb + (long)blk * 256 + h * 32);
    const unsigned int o2_0 = offp[q];
    const unsigned int o2_1 = offp[q + 8];
    const u16* lp = logit + (long)blk * 128 + h * 16;
    const float l0 = bf2f(lp[q]);
    const float l1 = bf2f(lp[q + 8]);

    // ---- softmax across the head's 8 lanes (16 logits) ----
    float m = fmaxf(l0, l1);
    m = fmaxf(m, __shfl_xor(m, 1));
    m = fmaxf(m, __shfl_xor(m, 2));
    m = fmaxf(m, __shfl_xor(m, 4));
    const float e0 = __expf(l0 - m);
    const float e1 = __expf(l1 - m);
    float se = e0 + e1;
    se += __shfl_xor(se, 1);
    se += __shfl_xor(se, 2);
    se += __shfl_xor(se, 4);
    const float inv = 1.f / se;
    const float aP0 = e0 * inv;
    const float aP1 = e1 * inv;

    // ---- per-point level constants (k0 in {0,1}, k1 in {2,3}) ----
    const int k0 = q >> 2;
    const int k1 = k0 + 2;
    const unsigned int LS0 = k0 ? 16384u : 0u;
    const unsigned int LS1 = k0 ? 21504u : 20480u;
    const unsigned int tb = (unsigned int)(b * STOT);
    const unsigned int hb64 = (unsigned int)(h * 64);
    const unsigned int base0 = (tb + LS0) * 512u + hb64;
    const unsigned int base1 = (tb + LS1) * 512u + hb64;

    float ww[8];
    unsigned int oo[8];
    point_corners(refx, refy, o2_0, aP0, k0, base0, ww,     oo);
    point_corners(refx, refy, o2_1, aP1, k1, base1, ww + 4, oo + 4);

    float2v acc[16];
#pragma unroll
    for (int n = 0; n < 16; ++n) { acc[n].x = 0.f; acc[n].y = 0.f; }

    const char* vp = (const char*)value;

    // ---- 4-corner-deep pipelined gather+accumulate ----
    uint4 A[4], B[4], C[4], D[4];
    LD_CORNER(A, oo[0]);
    LD_CORNER(B, oo[1]);
    LD_CORNER(C, oo[2]);
    LD_CORNER(D, oo[3]);
    FMA_CORNER(A, ww[0]); LD_CORNER(A, oo[4]);
    FMA_CORNER(B, ww[1]); LD_CORNER(B, oo[5]);
    FMA_CORNER(C, ww[2]); LD_CORNER(C, oo[6]);
    FMA_CORNER(D, ww[3]); LD_CORNER(D, oo[7]);
    FMA_CORNER(A, ww[4]);
    FMA_CORNER(B, ww[5]);
    FMA_CORNER(C, ww[6]);
    FMA_CORNER(D, ww[7]);

    // ---- in-wave reduce-scatter over the head's 8 lanes ----
    // acc[i] holds channels (2i, 2i+1); final: lane q keeps channels q*4..q*4+3
    float2v v8[8];
#pragma unroll
    for (int i = 0; i < 8; ++i) {
        const float2v snd = (q & 4) ? acc[i] : acc[i + 8];
        const float2v kp  = (q & 4) ? acc[i + 8] : acc[i];
        float2v r;
        r.x = __shfl_xor(snd.x, 4);
        r.y = __shfl_xor(snd.y, 4);
        v8[i] = kp + r;
    }
    float2v v4[4];
#pragma unroll
    for (int i = 0; i < 4; ++i) {
        const float2v snd = (q & 2) ? v8[i] : v8[i + 4];
        const float2v kp  = (q & 2) ? v8[i + 4] : v8[i];
        float2v r;
        r.x = __shfl_xor(snd.x, 2);
        r.y = __shfl_xor(snd.y, 2);
        v4[i] = kp + r;
    }
    float2v v2[2];
#pragma unroll
    for (int i = 0; i < 2; ++i) {
        const float2v snd = (q & 1) ? v4[i] : v4[i + 2];
        const float2v kp  = (q & 1) ? v4[i + 2] : v4[i];
        float2v r;
        r.x = __shfl_xor(snd.x, 1);
        r.y = __shfl_xor(snd.y, 1);
        v2[i] = kp + r;
    }

    ushort4 r;
    r.x = f2bf(v2[0].x); r.y = f2bf(v2[0].y);
    r.z = f2bf(v2[1].x); r.w = f2bf(v2[1].y);
    *(ushort4*)(sb + (long)blk * DMODEL + h * 32 + q * 4) = r;
}

// ---------------------------------------------------------------------------
// out = LayerNorm(out + delta_bf16); writes f32 residual + bf16 outb.
// If qb != null: also writes qb = bf16(LNout + posb) for next layer's q-GEMM.
// ---------------------------------------------------------------------------
__global__ __launch_bounds__(256)
void ln_kernel(float* __restrict__ out, u16* __restrict__ outb,
               u16* __restrict__ qb, const u16* __restrict__ posb,
               const u16* __restrict__ db,
               const float* __restrict__ gamma, const float* __restrict__ beta)
{
    const int wave = threadIdx.x >> 6;
    const int lane = threadIdx.x & 63;
    const long tok = (long)blockIdx.x * 4 + wave;
    float* op = out + tok * DMODEL + lane * 4;
    const float4 xo = *(const float4*)op;
    const ushort4 d4 = *(const ushort4*)(db + tok * DMODEL + lane * 4);
    float x[4] = {xo.x + bf2f(d4.x), xo.y + bf2f(d4.y),
                  xo.z + bf2f(d4.z), xo.w + bf2f(d4.w)};

    float sum = x[0] + x[1] + x[2] + x[3];
#pragma unroll
    for (int o = 32; o >= 1; o >>= 1) sum += __shfl_xor(sum, o);
    const float mean = sum * (1.f / 256.f);

    float vs = 0.f;
#pragma unroll
    for (int i = 0; i < 4; ++i) { const float d2 = x[i] - mean; vs += d2 * d2; }
#pragma unroll
    for (int o = 32; o >= 1; o >>= 1) vs += __shfl_xor(vs, o);
    const float rstd = rsqrtf(vs * (1.f / 256.f) + 1e-5f);

    const float4 g  = *(const float4*)(gamma + lane * 4);
    const float4 be = *(const float4*)(beta + lane * 4);
    float r[4];
    r[0] = (x[0] - mean) * rstd * g.x + be.x;
    r[1] = (x[1] - mean) * rstd * g.y + be.y;
    r[2] = (x[2] - mean) * rstd * g.z + be.z;
    r[3] = (x[3] - mean) * rstd * g.w + be.w;
    float4 rf; rf.x = r[0]; rf.y = r[1]; rf.z = r[2]; rf.w = r[3];
    *(float4*)op = rf;
    ushort4 rb;
    rb.x = f2bf(r[0]); rb.y = f2bf(r[1]); rb.z = f2bf(r[2]); rb.w = f2bf(r[3]);
    *(ushort4*)(outb + tok * DMODEL + lane * 4) = rb;
    if (qb) {
        const ushort4 p4 = *(const ushort4*)(posb + tok * DMODEL + lane * 4);
        ushort4 qv;
        qv.x = f2bf(r[0] + bf2f(p4.x));
        qv.y = f2bf(r[1] + bf2f(p4.y));
        qv.z = f2bf(r[2] + bf2f(p4.z));
        qv.w = f2bf(r[3] + bf2f(p4.w));
        *(ushort4*)(qb + tok * DMODEL + lane * 4) = qv;
    }
}

// ---------------------------------------------------------------------------
extern "C" void kernel_launch(void* const* d_in, const int* in_sizes, int n_in,
                              void* d_out, int out_size, void* d_ws, size_t ws_size,
                              hipStream_t stream)
{
    const float* src[4] = {(const float*)d_in[0], (const float*)d_in[2],
                           (const float*)d_in[4], (const float*)d_in[6]};
    const float* pos[4] = {(const float*)d_in[1], (const float*)d_in[3],
                           (const float*)d_in[5], (const float*)d_in[7]};
    const float* level_embed = (const float*)d_in[8];
    const float* Woff  = (const float*)d_in[9];
    const float* boff  = (const float*)d_in[10];
    const float* Wattn = (const float*)d_in[11];
    const float* battn = (const float*)d_in[12];
    const float* Wval  = (const float*)d_in[13];
    const float* bval  = (const float*)d_in[14];
    const float* Wout  = (const float*)d_in[15];
    const float* bout  = (const float*)d_in[16];
    const float* ln1s  = (const float*)d_in[17];
    const float* ln1b  = (const float*)d_in[18];
    const float* W1    = (const float*)d_in[19];
    const float* b1    = (const float*)d_in[20];
    const float* W2    = (const float*)d_in[21];
    const float* b2    = (const float*)d_in[22];
    const float* ln2s  = (const float*)d_in[23];
    const float* ln2b  = (const float*)d_in[24];

    float* out = (float*)d_out;                       // residual stream f32
    const long MD = (long)MTOT * DMODEL;              // 11,141,120

    // workspace layout (~187 MB)
    u16* outb = (u16*)d_ws;          // [M,256] LN output bf16
    u16* posb = outb + MD;           // [M,256] pos_flat bf16
    u16* qb   = posb + MD;           // [M,256] q = out+pos bf16
    u16* db   = qb + MD;             // [M,256] delta bf16 (attn_out / ff_out)
    u16* vb   = db + MD;             // [M,256] value bf16      (hb region start)
    u16* offb = vb + MD;             // [M,256] offsets bf16
    u16* awb  = offb + MD;           // [M,128] attn logits bf16
    u16* sb   = awb + MD / 2;        // [M,256] sampled bf16
    u16* hb   = vb;                  // [M,1024] FF hidden (aliases vb..sb+pad)
    u16* wts  = vb + 4 * MD;         // bf16 transposed weights
    u16* Wvalt = wts;
    u16* Wofat = Wvalt + 6L * 256 * 256;   // [384,256] per layer: Woff^T||Wattn^T
    u16* Woutt = Wofat + 6L * 384 * 256;
    u16* W1t   = Woutt + 6L * 256 * 256;
    u16* W2t   = W1t   + 6L * 1024 * 256;
    float* bias384 = (float*)(W2t + 6L * 1024 * 256);  // [NLAY][384]

    // ---- weight prep (every call; ~9 MB) ----
    biascat_kernel<<<9, 256, 0, stream>>>(boff, battn, bias384);
    wtrans_kernel<<<dim3(8, 8, 6),  256, 0, stream>>>(Wval,  Wvalt, 256, 256,
                                                      65536, 65536);
    wtrans_kernel<<<dim3(8, 8, 6),  256, 0, stream>>>(Woff,  Wofat, 256, 256,
                                                      65536, 98304);
    wtrans_kernel<<<dim3(4, 8, 6),  256, 0, stream>>>(Wattn, Wofat + 256 * 256,
                                                      256, 128, 32768, 98304);
    wtrans_kernel<<<dim3(8, 8, 6),  256, 0, stream>>>(Wout,  Woutt, 256, 256,
                                                      65536, 65536);
    wtrans_kernel<<<dim3(32, 8, 6), 256, 0, stream>>>(W1,    W1t, 256, 1024,
                                                      262144, 262144);
    wtrans_kernel<<<dim3(8, 32, 6), 256, 0, stream>>>(W2,    W2t, 1024, 256,
                                                      262144, 262144);

    // ---- flatten ----
    {
        const int HW[4] = {16384, 4096, 1024, 256};
        const int ST[4] = {0, 16384, 20480, 21504};
        for (int l = 0; l < 4; ++l) {
            dim3 g(HW[l] / 32, DMODEL / 32, NB);
            flatten_kernel<<<g, 256, 0, stream>>>(src[l], pos[l],
                                                  level_embed + l * DMODEL,
                                                  out, outb, posb, qb, HW[l], ST[l]);
        }
    }

    const dim3 g2(2, MTOT / 128);   // N=256
    const dim3 g3(3, MTOT / 128);   // N=384 (merged off||attn)
    const dim3 g8(8, MTOT / 128);   // N=1024 (FF1)

    for (int i = 0; i < NLAY; ++i) {
        const u16* Wv  = Wvalt + (long)i * 256 * 256;
        const u16* Wqa = Wofat + (long)i * 384 * 256;
        const u16* Wou = Woutt + (long)i * 256 * 256;
        const u16* W1i = W1t   + (long)i * 1024 * 256;
        const u16* W2i = W2t   + (long)i * 256 * 1024;
        const float* bv  = bval + (long)i * 256;
        const float* bqa = bias384 + (long)i * 384;
        const float* bou = bout + (long)i * 256;
        const float* b1i = b1   + (long)i * DFF;
        const float* b2i = b2   + (long)i * 256;

        // value = out @ Wval + bval -> vb bf16
        mfma_gemm<<<g2, 256, 0, stream>>>(outb, Wv, 256, bv,
                                          vb, 256, nullptr, 256, 0);
        // [off | attn logits] = q @ [Woff|Wattn] -> offb bf16, awb bf16
        mfma_gemm<<<g3, 256, 0, stream>>>(qb, Wqa, 256, bqa,
                                          offb, 256, awb, 256, 0);
        // sampling with fused softmax (reads logits directly)
        sample_kernel<<<MTOT / 4, 256, 0, stream>>>(vb, offb, awb, sb);
        // attn_out = s @ Wout + bout -> db bf16
        mfma_gemm<<<g2, 256, 0, stream>>>(sb, Wou, 256, bou,
                                          db, 256, nullptr, 256, 0);
        ln_kernel<<<MTOT / 4, 256, 0, stream>>>(out, outb, nullptr, nullptr, db,
                                                ln1s + (long)i * 256,
                                                ln1b + (long)i * 256);
        // FF: h = relu(out @ W1 + b1) -> hb bf16 [M,1024]
        mfma_gemm<<<g8, 256, 0, stream>>>(outb, W1i, 256, b1i,
                                          hb, 1024, nullptr, 256, 1);
        // ff_out = h @ W2 + b2 -> db bf16
        mfma_gemm<<<g2, 256, 0, stream>>>(hb, W2i, 1024, b2i,
                                          db, 256, nullptr, 1024, 0);
        ln_kernel<<<MTOT / 4, 256, 0, stream>>>(out, outb, qb, posb, db,
                                                ln2s + (long)i * 256,
                                                ln2b + (long)i * 256);
    }
}

// Round 4
// 1996.637 us; speedup vs baseline: 1.0712x; 1.0663x over previous
//
#include <hip/hip_runtime.h>
#include <math.h>

// Problem constants
#define DMODEL 256
#define NHEADS 8
#define NLAY 6
#define DFF 1024
#define DHEAD 32
#define NB 2
#define STOT 21760
#define MTOT (NB * STOT)   // 43520 = 128 * 340

typedef unsigned short u16;
typedef __attribute__((ext_vector_type(8))) short short8;
typedef __attribute__((ext_vector_type(4))) float floatx4;
typedef __attribute__((ext_vector_type(2))) float float2v;

__device__ __forceinline__ float bf2f(u16 h) {
    unsigned int u = ((unsigned int)h) << 16;
    return __uint_as_float(u);
}
__device__ __forceinline__ u16 f2bf(float f) {
    unsigned int u = __float_as_uint(f);
    u = u + 0x7fffu + ((u >> 16) & 1u);   // RNE
    return (u16)(u >> 16);
}

// packed dual-FMA: acc = a * b + acc (2 f32 lanes per instruction)
__device__ __forceinline__ void pkfma(float2v& acc, float2v a, float2v b) {
    asm("v_pk_fma_f32 %0, %1, %2, %0" : "+v"(acc) : "v"(a), "v"(b));
}
// packed bf16 pair (one uint) -> packed f32 pair
__device__ __forceinline__ float2v unpk(unsigned int u) {
    float2v r;
    r.x = __uint_as_float(u << 16);
    r.y = __uint_as_float(u & 0xffff0000u);
    return r;
}

// async global->LDS, 16B per lane. lds dest must be wave-uniform base
// (HW adds lane*16); global src is per-lane.
__device__ __forceinline__ void gload16(const u16* g, u16* l) {
    __builtin_amdgcn_global_load_lds(
        (const __attribute__((address_space(1))) unsigned int*)(g),
        (__attribute__((address_space(3))) unsigned int*)(l),
        16, 0, 0);
}

// ---------------------------------------------------------------------------
// Concatenated bias [NLAY][384] = boff[i] (256) || battn[i] (128)
// ---------------------------------------------------------------------------
__global__ __launch_bounds__(256)
void biascat_kernel(const float* __restrict__ boff, const float* __restrict__ battn,
                    float* __restrict__ bias384)
{
    const int t = blockIdx.x * 256 + threadIdx.x;
    if (t >= NLAY * 384) return;
    const int i = t / 384, c = t - i * 384;
    bias384[t] = (c < 256) ? boff[i * 256 + c] : battn[i * 128 + (c - 256)];
}

// ---------------------------------------------------------------------------
// Weight transpose + bf16 cast: W[K,N] f32 -> Wt[N,K] bf16.
// ---------------------------------------------------------------------------
__global__ __launch_bounds__(256)
void wtrans_kernel(const float* __restrict__ W, u16* __restrict__ Wt,
                   const int K, const int N, const long wstride, const long ostride)
{
    __shared__ float ts[32][33];
    W  += blockIdx.z * wstride;
    Wt += blockIdx.z * ostride;
    const int n0 = blockIdx.x * 32;
    const int k0 = blockIdx.y * 32;
    const int t = threadIdx.x;
    const int nl = t & 31, kl = t >> 5;        // kl 0..7
#pragma unroll
    for (int p = 0; p < 4; ++p) {
        const int k = kl + p * 8;
        ts[k][nl] = W[(long)(k0 + k) * N + n0 + nl];
    }
    __syncthreads();
    const int c = t & 31, r0 = t >> 5;
#pragma unroll
    for (int p = 0; p < 4; ++p) {
        const int r = r0 + p * 8;
        Wt[(long)(n0 + r) * K + k0 + c] = f2bf(ts[c][r]);
    }
}

// ---------------------------------------------------------------------------
// Flatten: src[b,d,y,x] -> out f32, outb bf16, posb bf16, qb = bf16(src+pos+le)
// ---------------------------------------------------------------------------
__global__ __launch_bounds__(256)
void flatten_kernel(const float* __restrict__ src, const float* __restrict__ pos,
                    const float* __restrict__ le_row,
                    float* __restrict__ out, u16* __restrict__ outb,
                    u16* __restrict__ posb, u16* __restrict__ qb,
                    int HW, int start)
{
    __shared__ float ts[32][33];
    __shared__ float tp[32][33];
    const int b   = blockIdx.z;
    const int d0  = blockIdx.y * 32;
    const int hw0 = blockIdx.x * 32;
    const int t   = threadIdx.x;
    const int hwl = t & 31;
    const int dl  = t >> 5;
#pragma unroll
    for (int p = 0; p < 4; ++p) {
        const int dd = dl + p * 8;
        const int d  = d0 + dd;
        const long idx = ((long)(b * DMODEL + d)) * HW + hw0 + hwl;
        ts[dd][hwl] = src[idx];
        tp[dd][hwl] = pos[idx] + le_row[d];
    }
    __syncthreads();
    const int dl2  = t & 31;
    const int hwl2 = t >> 5;
#pragma unroll
    for (int p = 0; p < 4; ++p) {
        const int hh  = hwl2 + p * 8;
        const int tok = start + hw0 + hh;
        const long o  = ((long)(b * STOT + tok)) * DMODEL + d0 + dl2;
        const float v = ts[dl2][hh];
        const float pp = tp[dl2][hh];
        out[o]  = v;
        outb[o] = f2bf(v);
        posb[o] = f2bf(pp);
        qb[o]   = f2bf(v + pp);
    }
}

// ---------------------------------------------------------------------------
// bf16 MFMA GEMM: Cb[M,N]bf16 = A[M,K]bf16 @ Bt[N,K]bf16^T + bias (relu opt)
// m97-structure staging: global_load_lds dwordx4 into linear [128][32] u16
// LDS (64B rows, no padding); fragments via single ds_read_b128.
// ---------------------------------------------------------------------------
__global__ __launch_bounds__(256)
void mfma_gemm(const u16* __restrict__ A, const u16* __restrict__ Bt,
               const int ldb, const float* __restrict__ bias,
               u16* __restrict__ Cb, const int ldc, u16* __restrict__ Cb2,
               const int K, const int relu)
{
    __shared__ u16 As[128 * 32];
    __shared__ u16 Bs[128 * 32];
    const int tid  = threadIdx.x;
    const int wv   = tid >> 6;
    const int lane = tid & 63;
    const int m0 = blockIdx.y * 128;
    const int n0 = blockIdx.x * 128;
    const int wm = (wv & 1) * 64;
    const int wn = (wv >> 1) * 64;
    const int q   = lane >> 4;
    const int c16 = lane & 15;

    // staging: chunk = it*4 + wv covers rows [chunk*16, chunk*16+16)
    // lane -> row = chunk*16 + lane/4, 16B col-slot = lane%4
    const int lrow = lane >> 2;
    const int lcol = (lane & 3) * 8;   // u16 units

    const u16* ag[2];
    const u16* bg[2];
#pragma unroll
    for (int it = 0; it < 2; ++it) {
        const int chunk = it * 4 + wv;
        const int row = chunk * 16 + lrow;
        ag[it] = A  + (long)(m0 + row) * K   + lcol;
        bg[it] = Bt + (long)(n0 + row) * ldb + lcol;
    }

    floatx4 acc[4][4];
#pragma unroll
    for (int i = 0; i < 4; ++i)
#pragma unroll
        for (int j = 0; j < 4; ++j)
            acc[i][j] = (floatx4){0.f, 0.f, 0.f, 0.f};

    for (int k0 = 0; k0 < K; k0 += 32) {
#pragma unroll
        for (int it = 0; it < 2; ++it) {
            const int chunk = it * 4 + wv;
            gload16(ag[it] + k0, &As[chunk * 512]);
            gload16(bg[it] + k0, &Bs[chunk * 512]);
        }
        __syncthreads();

        short8 af[4], bf[4];
#pragma unroll
        for (int i = 0; i < 4; ++i) {
            af[i] = *(const short8*)&As[(wm + i * 16 + c16) * 32 + q * 8];
            bf[i] = *(const short8*)&Bs[(wn + i * 16 + c16) * 32 + q * 8];
        }
#pragma unroll
        for (int i = 0; i < 4; ++i)
#pragma unroll
            for (int j = 0; j < 4; ++j)
                acc[i][j] = __builtin_amdgcn_mfma_f32_16x16x32_bf16(
                    af[i], bf[j], acc[i][j], 0, 0, 0);
        __syncthreads();
    }

    // output selection (block-uniform)
    u16* cb  = Cb;
    int ldcb = ldc, csub = 0;
    if (Cb2 && n0 >= 256) { cb = Cb2; ldcb = 128; csub = 256; }

#pragma unroll
    for (int i = 0; i < 4; ++i) {
#pragma unroll
        for (int j = 0; j < 4; ++j) {
            const int col = n0 + wn + j * 16 + c16;
            const float bv = bias ? bias[col] : 0.f;
#pragma unroll
            for (int r = 0; r < 4; ++r) {
                const int row = m0 + wm + i * 16 + q * 4 + r;
                float v = acc[i][j][r] + bv;
                if (relu) v = fmaxf(v, 0.f);
                cb[(long)row * ldcb + col - csub] = f2bf(v);
            }
        }
    }
}

// ---------------------------------------------------------------------------
// Deformable sampling — hybrid decomposition.
// Phase 1 (point-parallel): lane (h, u) computes corners+weights for points
// {u, u+8} of head h (softmax folded in, via 8-lane shfl reduce).
// Phase 2 (coalesced gather): per group of 4 points, shfl-broadcast the 16
// (w, o) pairs to all 8 head-lanes; each lane loads its 8B channel slice
// (lane u -> channels u*4..u*4+3) for 16 corners back-to-back, then pkfma.
// Gathers are 64B-contiguous per head per corner => 8 lines/instruction.
// ---------------------------------------------------------------------------
__device__ __forceinline__ void point_corners(
    float refx, float refy, unsigned int o2, float aP,
    int k, unsigned int base, float* w, unsigned int* o)
{
    const int lw = 128 >> k;
    const float flw = (float)lw;
    const float x = refx * flw - 0.5f + bf2f((u16)(o2 & 0xffffu));
    const float y = refy * flw - 0.5f + bf2f((u16)(o2 >> 16));
    const float x0f = floorf(x), y0f = floorf(y);
    const float lx = x - x0f, ly = y - y0f;
    const int x0 = (int)x0f, y0 = (int)y0f;
    const float wx0 = ((unsigned int)x0 < (unsigned int)lw) ? (1.f - lx) : 0.f;
    const float wx1 = ((unsigned int)(x0 + 1) < (unsigned int)lw) ? lx : 0.f;
    const float wy0 = ((unsigned int)y0 < (unsigned int)lw) ? (aP * (1.f - ly)) : 0.f;
    const float wy1 = ((unsigned int)(y0 + 1) < (unsigned int)lw) ? (aP * ly) : 0.f;
    // byte offsets: token stride 512B; row stride lw*512 = 1<<(16-k)
    const unsigned int xc0 = (unsigned int)(x0 & (lw - 1)) << 9;
    const unsigned int xc1 = (unsigned int)((x0 + 1) & (lw - 1)) << 9;
    const unsigned int r0 = (unsigned int)(y0 & (lw - 1)) << (16 - k);
    const unsigned int r1 = (unsigned int)((y0 + 1) & (lw - 1)) << (16 - k);
    w[0] = wy0 * wx0; o[0] = base + r0 + xc0;
    w[1] = wy0 * wx1; o[1] = base + r0 + xc1;
    w[2] = wy1 * wx0; o[2] = base + r1 + xc0;
    w[3] = wy1 * wx1; o[3] = base + r1 + xc1;
}

__global__ __launch_bounds__(256, 4)
void sample_kernel(const u16* __restrict__ value, const u16* __restrict__ offb,
                   const u16* __restrict__ logit, u16* __restrict__ sb)
{
    const int t  = threadIdx.x;
    const int wv = t >> 6;                 // token slot within block
    const int l  = t & 63;
    const int h  = l >> 3;                 // head 0..7
    const int u  = l & 7;                  // point-pair owner / channel slice
    const int blk = blockIdx.x * 4 + wv;   // global token
    const int b = blk / STOT;
    const int s = blk - b * STOT;

    float refx, refy;
    if (s < 16384) {
        const int yy = s >> 7, xx = s & 127;
        refx = (xx + 0.5f) * (1.f / 128.f); refy = (yy + 0.5f) * (1.f / 128.f);
    } else if (s < 20480) {
        const int sl = s - 16384; const int yy = sl >> 6, xx = sl & 63;
        refx = (xx + 0.5f) * (1.f / 64.f);  refy = (yy + 0.5f) * (1.f / 64.f);
    } else if (s < 21504) {
        const int sl = s - 20480; const int yy = sl >> 5, xx = sl & 31;
        refx = (xx + 0.5f) * (1.f / 32.f);  refy = (yy + 0.5f) * (1.f / 32.f);
    } else {
        const int sl = s - 21504; const int yy = sl >> 4, xx = sl & 15;
        refx = (xx + 0.5f) * (1.f / 16.f);  refy = (yy + 0.5f) * (1.f / 16.f);
    }

    // ---- phase 1: this lane's 2 points ----
    const unsigned int* offp = (const unsigned int*)(offb + (long)blk * 256 + h * 32);
    const unsigned int o2_0 = offp[u];
    const unsigned int o2_1 = offp[u + 8];
    const u16* lp = logit + (long)blk * 128 + h * 16;
    const float l0 = bf2f(lp[u]);
    const float l1 = bf2f(lp[u + 8]);

    // softmax across the head's 8 lanes (16 logits)
    float m = fmaxf(l0, l1);
    m = fmaxf(m, __shfl_xor(m, 1));
    m = fmaxf(m, __shfl_xor(m, 2));
    m = fmaxf(m, __shfl_xor(m, 4));
    const float e0 = __expf(l0 - m);
    const float e1 = __expf(l1 - m);
    float se = e0 + e1;
    se += __shfl_xor(se, 1);
    se += __shfl_xor(se, 2);
    se += __shfl_xor(se, 4);
    const float inv = 1.f / se;
    const float aP0 = e0 * inv;
    const float aP1 = e1 * inv;

    // levels: point u -> level u>>2 (0/1), point u+8 -> level (u>>2)+2 (2/3)
    const int k0 = u >> 2;
    const unsigned int LS0 = k0 ? 16384u : 0u;
    const unsigned int LS1 = k0 ? 21504u : 20480u;
    const unsigned int tb = (unsigned int)(b * STOT);
    const unsigned int hb64 = (unsigned int)(h * 64);
    const unsigned int base0 = (tb + LS0) * 512u + hb64;
    const unsigned int base1 = (tb + LS1) * 512u + hb64;

    float ww[8];
    unsigned int oo[8];
    point_corners(refx, refy, o2_0, aP0, k0,     base0, ww,     oo);
    point_corners(refx, refy, o2_1, aP1, k0 + 2, base1, ww + 4, oo + 4);

    // ---- phase 2: coalesced gathers, 4 points per batch ----
    const int sbase = l & 56;              // first lane of this head
    const unsigned int chb = (unsigned int)(u * 8);  // channel byte offset
    const char* vp = (const char*)value;
    float2v acc0; acc0.x = 0.f; acc0.y = 0.f;
    float2v acc1; acc1.x = 0.f; acc1.y = 0.f;

#pragma unroll
    for (int g = 0; g < 4; ++g) {
        float wB[16];
        unsigned int oB[16];
        uint2 dB[16];
#pragma unroll
        for (int pp = 0; pp < 4; ++pp) {
            const int p = g * 4 + pp;
            const int src = sbase + (p & 7);
            const int slotbase = (p >> 3) * 4;
#pragma unroll
            for (int c = 0; c < 4; ++c) {
                oB[pp * 4 + c] = (unsigned int)__shfl((int)oo[slotbase + c], src);
                wB[pp * 4 + c] = __shfl(ww[slotbase + c], src);
            }
        }
#pragma unroll
        for (int i = 0; i < 16; ++i)
            dB[i] = *(const uint2*)(vp + (oB[i] + chb));
#pragma unroll
        for (int i = 0; i < 16; ++i) {
            float2v w2; w2.x = wB[i]; w2.y = wB[i];
            pkfma(acc0, w2, unpk(dB[i].x));
            pkfma(acc1, w2, unpk(dB[i].y));
        }
    }

    ushort4 r;
    r.x = f2bf(acc0.x); r.y = f2bf(acc0.y);
    r.z = f2bf(acc1.x); r.w = f2bf(acc1.y);
    *(ushort4*)(sb + (long)blk * DMODEL + h * 32 + u * 4) = r;
}

// ---------------------------------------------------------------------------
// out = LayerNorm(out + delta_bf16); writes f32 residual + bf16 outb.
// If qb != null: also writes qb = bf16(LNout + posb) for next layer's q-GEMM.
// ---------------------------------------------------------------------------
__global__ __launch_bounds__(256)
void ln_kernel(float* __restrict__ out, u16* __restrict__ outb,
               u16* __restrict__ qb, const u16* __restrict__ posb,
               const u16* __restrict__ db,
               const float* __restrict__ gamma, const float* __restrict__ beta)
{
    const int wave = threadIdx.x >> 6;
    const int lane = threadIdx.x & 63;
    const long tok = (long)blockIdx.x * 4 + wave;
    float* op = out + tok * DMODEL + lane * 4;
    const float4 xo = *(const float4*)op;
    const ushort4 d4 = *(const ushort4*)(db + tok * DMODEL + lane * 4);
    float x[4] = {xo.x + bf2f(d4.x), xo.y + bf2f(d4.y),
                  xo.z + bf2f(d4.z), xo.w + bf2f(d4.w)};

    float sum = x[0] + x[1] + x[2] + x[3];
#pragma unroll
    for (int o = 32; o >= 1; o >>= 1) sum += __shfl_xor(sum, o);
    const float mean = sum * (1.f / 256.f);

    float vs = 0.f;
#pragma unroll
    for (int i = 0; i < 4; ++i) { const float d2 = x[i] - mean; vs += d2 * d2; }
#pragma unroll
    for (int o = 32; o >= 1; o >>= 1) vs += __shfl_xor(vs, o);
    const float rstd = rsqrtf(vs * (1.f / 256.f) + 1e-5f);

    const float4 g  = *(const float4*)(gamma + lane * 4);
    const float4 be = *(const float4*)(beta + lane * 4);
    float r[4];
    r[0] = (x[0] - mean) * rstd * g.x + be.x;
    r[1] = (x[1] - mean) * rstd * g.y + be.y;
    r[2] = (x[2] - mean) * rstd * g.z + be.z;
    r[3] = (x[3] - mean) * rstd * g.w + be.w;
    float4 rf; rf.x = r[0]; rf.y = r[1]; rf.z = r[2]; rf.w = r[3];
    *(float4*)op = rf;
    ushort4 rb;
    rb.x = f2bf(r[0]); rb.y = f2bf(r[1]); rb.z = f2bf(r[2]); rb.w = f2bf(r[3]);
    *(ushort4*)(outb + tok * DMODEL + lane * 4) = rb;
    if (qb) {
        const ushort4 p4 = *(const ushort4*)(posb + tok * DMODEL + lane * 4);
        ushort4 qv;
        qv.x = f2bf(r[0] + bf2f(p4.x));
        qv.y = f2bf(r[1] + bf2f(p4.y));
        qv.z = f2bf(r[2] + bf2f(p4.z));
        qv.w = f2bf(r[3] + bf2f(p4.w));
        *(ushort4*)(qb + tok * DMODEL + lane * 4) = qv;
    }
}

// ---------------------------------------------------------------------------
extern "C" void kernel_launch(void* const* d_in, const int* in_sizes, int n_in,
                              void* d_out, int out_size, void* d_ws, size_t ws_size,
                              hipStream_t stream)
{
    const float* src[4] = {(const float*)d_in[0], (const float*)d_in[2],
                           (const float*)d_in[4], (const float*)d_in[6]};
    const float* pos[4] = {(const float*)d_in[1], (const float*)d_in[3],
                           (const float*)d_in[5], (const float*)d_in[7]};
    const float* level_embed = (const float*)d_in[8];
    const float* Woff  = (const float*)d_in[9];
    const float* boff  = (const float*)d_in[10];
    const float* Wattn = (const float*)d_in[11];
    const float* battn = (const float*)d_in[12];
    const float* Wval  = (const float*)d_in[13];
    const float* bval  = (const float*)d_in[14];
    const float* Wout  = (const float*)d_in[15];
    const float* bout  = (const float*)d_in[16];
    const float* ln1s  = (const float*)d_in[17];
    const float* ln1b  = (const float*)d_in[18];
    const float* W1    = (const float*)d_in[19];
    const float* b1    = (const float*)d_in[20];
    const float* W2    = (const float*)d_in[21];
    const float* b2    = (const float*)d_in[22];
    const float* ln2s  = (const float*)d_in[23];
    const float* ln2b  = (const float*)d_in[24];

    float* out = (float*)d_out;                       // residual stream f32
    const long MD = (long)MTOT * DMODEL;              // 11,141,120

    // workspace layout (~187 MB)
    u16* outb = (u16*)d_ws;          // [M,256] LN output bf16
    u16* posb = outb + MD;           // [M,256] pos_flat bf16
    u16* qb   = posb + MD;           // [M,256] q = out+pos bf16
    u16* db   = qb + MD;             // [M,256] delta bf16 (attn_out / ff_out)
    u16* vb   = db + MD;             // [M,256] value bf16      (hb region start)
    u16* offb = vb + MD;             // [M,256] offsets bf16
    u16* awb  = offb + MD;           // [M,128] attn logits bf16
    u16* sb   = awb + MD / 2;        // [M,256] sampled bf16
    u16* hb   = vb;                  // [M,1024] FF hidden (aliases vb..sb+pad)
    u16* wts  = vb + 4 * MD;         // bf16 transposed weights
    u16* Wvalt = wts;
    u16* Wofat = Wvalt + 6L * 256 * 256;   // [384,256] per layer: Woff^T||Wattn^T
    u16* Woutt = Wofat + 6L * 384 * 256;
    u16* W1t   = Woutt + 6L * 256 * 256;
    u16* W2t   = W1t   + 6L * 1024 * 256;
    float* bias384 = (float*)(W2t + 6L * 1024 * 256);  // [NLAY][384]

    // ---- weight prep (every call; ~9 MB) ----
    biascat_kernel<<<9, 256, 0, stream>>>(boff, battn, bias384);
    wtrans_kernel<<<dim3(8, 8, 6),  256, 0, stream>>>(Wval,  Wvalt, 256, 256,
                                                      65536, 65536);
    wtrans_kernel<<<dim3(8, 8, 6),  256, 0, stream>>>(Woff,  Wofat, 256, 256,
                                                      65536, 98304);
    wtrans_kernel<<<dim3(4, 8, 6),  256, 0, stream>>>(Wattn, Wofat + 256 * 256,
                                                      256, 128, 32768, 98304);
    wtrans_kernel<<<dim3(8, 8, 6),  256, 0, stream>>>(Wout,  Woutt, 256, 256,
                                                      65536, 65536);
    wtrans_kernel<<<dim3(32, 8, 6), 256, 0, stream>>>(W1,    W1t, 256, 1024,
                                                      262144, 262144);
    wtrans_kernel<<<dim3(8, 32, 6), 256, 0, stream>>>(W2,    W2t, 1024, 256,
                                                      262144, 262144);

    // ---- flatten ----
    {
        const int HW[4] = {16384, 4096, 1024, 256};
        const int ST[4] = {0, 16384, 20480, 21504};
        for (int l = 0; l < 4; ++l) {
            dim3 g(HW[l] / 32, DMODEL / 32, NB);
            flatten_kernel<<<g, 256, 0, stream>>>(src[l], pos[l],
                                                  level_embed + l * DMODEL,
                                                  out, outb, posb, qb, HW[l], ST[l]);
        }
    }

    const dim3 g2(2, MTOT / 128);   // N=256
    const dim3 g3(3, MTOT / 128);   // N=384 (merged off||attn)
    const dim3 g8(8, MTOT / 128);   // N=1024 (FF1)

    for (int i = 0; i < NLAY; ++i) {
        const u16* Wv  = Wvalt + (long)i * 256 * 256;
        const u16* Wqa = Wofat + (long)i * 384 * 256;
        const u16* Wou = Woutt + (long)i * 256 * 256;
        const u16* W1i = W1t   + (long)i * 1024 * 256;
        const u16* W2i = W2t   + (long)i * 256 * 1024;
        const float* bv  = bval + (long)i * 256;
        const float* bqa = bias384 + (long)i * 384;
        const float* bou = bout + (long)i * 256;
        const float* b1i = b1   + (long)i * DFF;
        const float* b2i = b2   + (long)i * 256;

        // value = out @ Wval + bval -> vb bf16
        mfma_gemm<<<g2, 256, 0, stream>>>(outb, Wv, 256, bv,
                                          vb, 256, nullptr, 256, 0);
        // [off | attn logits] = q @ [Woff|Wattn] -> offb bf16, awb bf16
        mfma_gemm<<<g3, 256, 0, stream>>>(qb, Wqa, 256, bqa,
                                          offb, 256, awb, 256, 0);
        // sampling with fused softmax (reads logits directly)
        sample_kernel<<<MTOT / 4, 256, 0, stream>>>(vb, offb, awb, sb);
        // attn_out = s @ Wout + bout -> db bf16
        mfma_gemm<<<g2, 256, 0, stream>>>(sb, Wou, 256, bou,
                                          db, 256, nullptr, 256, 0);
        ln_kernel<<<MTOT / 4, 256, 0, stream>>>(out, outb, nullptr, nullptr, db,
                                                ln1s + (long)i * 256,
                                                ln1b + (long)i * 256);
        // FF: h = relu(out @ W1 + b1) -> hb bf16 [M,1024]
        mfma_gemm<<<g8, 256, 0, stream>>>(outb, W1i, 256, b1i,
                                          hb, 1024, nullptr, 256, 1);
        // ff_out = h @ W2 + b2 -> db bf16
        mfma_gemm<<<g2, 256, 0, stream>>>(hb, W2i, 1024, b2i,
                                          db, 256, nullptr, 1024, 0);
        ln_kernel<<<MTOT / 4, 256, 0, stream>>>(out, outb, qb, posb, db,
                                                ln2s + (long)i * 256,
                                                ln2b + (long)i * 256);
    }
}

// Round 5
// 1900.194 us; speedup vs baseline: 1.1256x; 1.0508x over previous
//
#include <hip/hip_runtime.h>
#include <math.h>

// Problem constants
#define DMODEL 256
#define NHEADS 8
#define NLAY 6
#define DFF 1024
#define DHEAD 32
#define NB 2
#define STOT 21760
#define MTOT (NB * STOT)   // 43520 = 128 * 340

typedef unsigned short u16;
typedef __attribute__((ext_vector_type(8))) short short8;
typedef __attribute__((ext_vector_type(4))) float floatx4;
typedef __attribute__((ext_vector_type(2))) float float2v;

__device__ __forceinline__ float bf2f(u16 h) {
    unsigned int u = ((unsigned int)h) << 16;
    return __uint_as_float(u);
}
__device__ __forceinline__ u16 f2bf(float f) {
    unsigned int u = __float_as_uint(f);
    u = u + 0x7fffu + ((u >> 16) & 1u);   // RNE
    return (u16)(u >> 16);
}

// packed dual-FMA: acc = a * b + acc (2 f32 lanes per instruction)
__device__ __forceinline__ void pkfma(float2v& acc, float2v a, float2v b) {
    asm("v_pk_fma_f32 %0, %1, %2, %0" : "+v"(acc) : "v"(a), "v"(b));
}
// packed bf16 pair (one uint) -> packed f32 pair
__device__ __forceinline__ float2v unpk(unsigned int u) {
    float2v r;
    r.x = __uint_as_float(u << 16);
    r.y = __uint_as_float(u & 0xffff0000u);
    return r;
}

// async global->LDS, 16B per lane. lds dest must be wave-uniform base
// (HW adds lane*16); global src is per-lane.
__device__ __forceinline__ void gload16(const u16* g, u16* l) {
    __builtin_amdgcn_global_load_lds(
        (const __attribute__((address_space(1))) unsigned int*)(g),
        (__attribute__((address_space(3))) unsigned int*)(l),
        16, 0, 0);
}

// ---------------------------------------------------------------------------
// Concatenated bias [NLAY][384] = boff[i] (256) || battn[i] (128)
// ---------------------------------------------------------------------------
__global__ __launch_bounds__(256)
void biascat_kernel(const float* __restrict__ boff, const float* __restrict__ battn,
                    float* __restrict__ bias384)
{
    const int t = blockIdx.x * 256 + threadIdx.x;
    if (t >= NLAY * 384) return;
    const int i = t / 384, c = t - i * 384;
    bias384[t] = (c < 256) ? boff[i * 256 + c] : battn[i * 128 + (c - 256)];
}

// ---------------------------------------------------------------------------
// Weight transpose + bf16 cast: W[K,N] f32 -> Wt[N,K] bf16.
// ---------------------------------------------------------------------------
__global__ __launch_bounds__(256)
void wtrans_kernel(const float* __restrict__ W, u16* __restrict__ Wt,
                   const int K, const int N, const long wstride, const long ostride)
{
    __shared__ float ts[32][33];
    W  += blockIdx.z * wstride;
    Wt += blockIdx.z * ostride;
    const int n0 = blockIdx.x * 32;
    const int k0 = blockIdx.y * 32;
    const int t = threadIdx.x;
    const int nl = t & 31, kl = t >> 5;        // kl 0..7
#pragma unroll
    for (int p = 0; p < 4; ++p) {
        const int k = kl + p * 8;
        ts[k][nl] = W[(long)(k0 + k) * N + n0 + nl];
    }
    __syncthreads();
    const int c = t & 31, r0 = t >> 5;
#pragma unroll
    for (int p = 0; p < 4; ++p) {
        const int r = r0 + p * 8;
        Wt[(long)(n0 + r) * K + k0 + c] = f2bf(ts[c][r]);
    }
}

// ---------------------------------------------------------------------------
// Flatten: src[b,d,y,x] -> out f32, outb bf16, posb bf16, qb = bf16(src+pos+le)
// ---------------------------------------------------------------------------
__global__ __launch_bounds__(256)
void flatten_kernel(const float* __restrict__ src, const float* __restrict__ pos,
                    const float* __restrict__ le_row,
                    float* __restrict__ out, u16* __restrict__ outb,
                    u16* __restrict__ posb, u16* __restrict__ qb,
                    int HW, int start)
{
    __shared__ float ts[32][33];
    __shared__ float tp[32][33];
    const int b   = blockIdx.z;
    const int d0  = blockIdx.y * 32;
    const int hw0 = blockIdx.x * 32;
    const int t   = threadIdx.x;
    const int hwl = t & 31;
    const int dl  = t >> 5;
#pragma unroll
    for (int p = 0; p < 4; ++p) {
        const int dd = dl + p * 8;
        const int d  = d0 + dd;
        const long idx = ((long)(b * DMODEL + d)) * HW + hw0 + hwl;
        ts[dd][hwl] = src[idx];
        tp[dd][hwl] = pos[idx] + le_row[d];
    }
    __syncthreads();
    const int dl2  = t & 31;
    const int hwl2 = t >> 5;
#pragma unroll
    for (int p = 0; p < 4; ++p) {
        const int hh  = hwl2 + p * 8;
        const int tok = start + hw0 + hh;
        const long o  = ((long)(b * STOT + tok)) * DMODEL + d0 + dl2;
        const float v = ts[dl2][hh];
        const float pp = tp[dl2][hh];
        out[o]  = v;
        outb[o] = f2bf(v);
        posb[o] = f2bf(pp);
        qb[o]   = f2bf(v + pp);
    }
}

// ---------------------------------------------------------------------------
// bf16 MFMA GEMM: Cb[M,N]bf16 = A[M,K]bf16 @ Bt[N,K]bf16^T + bias (relu opt)
// Double-buffered global_load_lds pipeline: STAGE(next) overlaps ds_read+MFMA
// of current tile; one barrier per K-step (drains vmcnt for next tile AND
// protects the buffer being overwritten next iteration).
// ---------------------------------------------------------------------------
__global__ __launch_bounds__(256)
void mfma_gemm(const u16* __restrict__ A, const u16* __restrict__ Bt,
               const int ldb, const float* __restrict__ bias,
               u16* __restrict__ Cb, const int ldc, u16* __restrict__ Cb2,
               const int K, const int relu)
{
    __shared__ u16 As[2][128 * 32];
    __shared__ u16 Bs[2][128 * 32];
    const int tid  = threadIdx.x;
    const int wv   = tid >> 6;
    const int lane = tid & 63;
    const int m0 = blockIdx.y * 128;
    const int n0 = blockIdx.x * 128;
    const int wm = (wv & 1) * 64;
    const int wn = (wv >> 1) * 64;
    const int q   = lane >> 4;
    const int c16 = lane & 15;

    // staging: chunk = it*4 + wv covers rows [chunk*16, chunk*16+16)
    const int lrow = lane >> 2;
    const int lcol = (lane & 3) * 8;   // u16 units

    const u16* ag[2];
    const u16* bg[2];
#pragma unroll
    for (int it = 0; it < 2; ++it) {
        const int chunk = it * 4 + wv;
        const int row = chunk * 16 + lrow;
        ag[it] = A  + (long)(m0 + row) * K   + lcol;
        bg[it] = Bt + (long)(n0 + row) * ldb + lcol;
    }

#define STAGE(buf, kk)                                          \
    {                                                           \
        _Pragma("unroll")                                       \
        for (int it = 0; it < 2; ++it) {                        \
            const int chunk = it * 4 + wv;                      \
            gload16(ag[it] + (kk), &As[buf][chunk * 512]);      \
            gload16(bg[it] + (kk), &Bs[buf][chunk * 512]);      \
        }                                                       \
    }

    floatx4 acc[4][4];
#pragma unroll
    for (int i = 0; i < 4; ++i)
#pragma unroll
        for (int j = 0; j < 4; ++j)
            acc[i][j] = (floatx4){0.f, 0.f, 0.f, 0.f};

    STAGE(0, 0);
    __syncthreads();

    int cur = 0;
    for (int k0 = 0; k0 < K; k0 += 32) {
        const int nxt = k0 + 32;
        if (nxt < K) {
            if (cur) { STAGE(0, nxt); } else { STAGE(1, nxt); }
        }

        const u16* Ab = &As[cur][0];
        const u16* Bb = &Bs[cur][0];
        short8 af[4], bf[4];
#pragma unroll
        for (int i = 0; i < 4; ++i) {
            af[i] = *(const short8*)&Ab[(wm + i * 16 + c16) * 32 + q * 8];
            bf[i] = *(const short8*)&Bb[(wn + i * 16 + c16) * 32 + q * 8];
        }
#pragma unroll
        for (int i = 0; i < 4; ++i)
#pragma unroll
            for (int j = 0; j < 4; ++j)
                acc[i][j] = __builtin_amdgcn_mfma_f32_16x16x32_bf16(
                    af[i], bf[j], acc[i][j], 0, 0, 0);
        __syncthreads();
        cur ^= 1;
    }
#undef STAGE

    // output selection (block-uniform)
    u16* cb  = Cb;
    int ldcb = ldc, csub = 0;
    if (Cb2 && n0 >= 256) { cb = Cb2; ldcb = 128; csub = 256; }

#pragma unroll
    for (int i = 0; i < 4; ++i) {
#pragma unroll
        for (int j = 0; j < 4; ++j) {
            const int col = n0 + wn + j * 16 + c16;
            const float bv = bias ? bias[col] : 0.f;
#pragma unroll
            for (int r = 0; r < 4; ++r) {
                const int row = m0 + wm + i * 16 + q * 4 + r;
                float v = acc[i][j][r] + bv;
                if (relu) v = fmaxf(v, 0.f);
                cb[(long)row * ldcb + col - csub] = f2bf(v);
            }
        }
    }
}

// ---------------------------------------------------------------------------
// Deformable sampling — hybrid decomposition, LDS-broadcast (w,o) table.
// Phase 1 (point-parallel): lane (h, u) computes corners+weights for points
// {u, u+8} of head h (softmax folded in via 8-lane shfl reduce), writes the
// 8 (w, o) pairs to a per-head LDS table (528B stride -> disjoint banks).
// Phase 2 (coalesced gather): per group of 4 points, all 8 head-lanes read
// the same 128B of pairs (broadcast, conflict-free) with 8 ds_read_b128,
// then issue 16 uint2 gathers (64B contiguous per head) + 32 pkfma.
// ---------------------------------------------------------------------------
__device__ __forceinline__ void point_corners(
    float refx, float refy, unsigned int o2, float aP,
    int k, unsigned int base, float* w, unsigned int* o)
{
    const int lw = 128 >> k;
    const float flw = (float)lw;
    const float x = refx * flw - 0.5f + bf2f((u16)(o2 & 0xffffu));
    const float y = refy * flw - 0.5f + bf2f((u16)(o2 >> 16));
    const float x0f = floorf(x), y0f = floorf(y);
    const float lx = x - x0f, ly = y - y0f;
    const int x0 = (int)x0f, y0 = (int)y0f;
    const float wx0 = ((unsigned int)x0 < (unsigned int)lw) ? (1.f - lx) : 0.f;
    const float wx1 = ((unsigned int)(x0 + 1) < (unsigned int)lw) ? lx : 0.f;
    const float wy0 = ((unsigned int)y0 < (unsigned int)lw) ? (aP * (1.f - ly)) : 0.f;
    const float wy1 = ((unsigned int)(y0 + 1) < (unsigned int)lw) ? (aP * ly) : 0.f;
    // byte offsets: token stride 512B; row stride lw*512 = 1<<(16-k)
    const unsigned int xc0 = (unsigned int)(x0 & (lw - 1)) << 9;
    const unsigned int xc1 = (unsigned int)((x0 + 1) & (lw - 1)) << 9;
    const unsigned int r0 = (unsigned int)(y0 & (lw - 1)) << (16 - k);
    const unsigned int r1 = (unsigned int)((y0 + 1) & (lw - 1)) << (16 - k);
    w[0] = wy0 * wx0; o[0] = base + r0 + xc0;
    w[1] = wy0 * wx1; o[1] = base + r0 + xc1;
    w[2] = wy1 * wx0; o[2] = base + r1 + xc0;
    w[3] = wy1 * wx1; o[3] = base + r1 + xc1;
}

__global__ __launch_bounds__(256, 4)
void sample_kernel(const u16* __restrict__ value, const u16* __restrict__ offb,
                   const u16* __restrict__ logit, u16* __restrict__ sb)
{
    // per wave: 8 heads x 132 uints (512B payload + 16B pad) = 4224B
    __shared__ unsigned int pwtab[4 * 8 * 132];

    const int t  = threadIdx.x;
    const int wv = t >> 6;                 // token slot within block
    const int l  = t & 63;
    const int h  = l >> 3;                 // head 0..7
    const int u  = l & 7;                  // point-pair owner / channel slice
    const int blk = blockIdx.x * 4 + wv;   // global token
    const int b = blk / STOT;
    const int s = blk - b * STOT;

    float refx, refy;
    if (s < 16384) {
        const int yy = s >> 7, xx = s & 127;
        refx = (xx + 0.5f) * (1.f / 128.f); refy = (yy + 0.5f) * (1.f / 128.f);
    } else if (s < 20480) {
        const int sl = s - 16384; const int yy = sl >> 6, xx = sl & 63;
        refx = (xx + 0.5f) * (1.f / 64.f);  refy = (yy + 0.5f) * (1.f / 64.f);
    } else if (s < 21504) {
        const int sl = s - 20480; const int yy = sl >> 5, xx = sl & 31;
        refx = (xx + 0.5f) * (1.f / 32.f);  refy = (yy + 0.5f) * (1.f / 32.f);
    } else {
        const int sl = s - 21504; const int yy = sl >> 4, xx = sl & 15;
        refx = (xx + 0.5f) * (1.f / 16.f);  refy = (yy + 0.5f) * (1.f / 16.f);
    }

    // ---- phase 1: this lane's 2 points ----
    const unsigned int* offp = (const unsigned int*)(offb + (long)blk * 256 + h * 32);
    const unsigned int o2_0 = offp[u];
    const unsigned int o2_1 = offp[u + 8];
    const u16* lp = logit + (long)blk * 128 + h * 16;
    const float l0 = bf2f(lp[u]);
    const float l1 = bf2f(lp[u + 8]);

    // softmax across the head's 8 lanes (16 logits)
    float m = fmaxf(l0, l1);
    m = fmaxf(m, __shfl_xor(m, 1));
    m = fmaxf(m, __shfl_xor(m, 2));
    m = fmaxf(m, __shfl_xor(m, 4));
    const float e0 = __expf(l0 - m);
    const float e1 = __expf(l1 - m);
    float se = e0 + e1;
    se += __shfl_xor(se, 1);
    se += __shfl_xor(se, 2);
    se += __shfl_xor(se, 4);
    const float inv = 1.f / se;
    const float aP0 = e0 * inv;
    const float aP1 = e1 * inv;

    // levels: point u -> level u>>2 (0/1), point u+8 -> level (u>>2)+2 (2/3)
    const int k0 = u >> 2;
    const unsigned int LS0 = k0 ? 16384u : 0u;
    const unsigned int LS1 = k0 ? 21504u : 20480u;
    const unsigned int tb = (unsigned int)(b * STOT);
    const unsigned int hb64 = (unsigned int)(h * 64);
    const unsigned int base0 = (tb + LS0) * 512u + hb64;
    const unsigned int base1 = (tb + LS1) * 512u + hb64;

    float ww[8];
    unsigned int oo[8];
    point_corners(refx, refy, o2_0, aP0, k0,     base0, ww,     oo);
    point_corners(refx, refy, o2_1, aP1, k0 + 2, base1, ww + 4, oo + 4);

    // ---- publish (w,o) pairs to the per-head LDS table ----
    unsigned int* wbase = pwtab + (wv * 8 + h) * 132;
    {
        uint4 p0, p1, p2, p3;
        p0.x = __float_as_uint(ww[0]); p0.y = oo[0];
        p0.z = __float_as_uint(ww[1]); p0.w = oo[1];
        p1.x = __float_as_uint(ww[2]); p1.y = oo[2];
        p1.z = __float_as_uint(ww[3]); p1.w = oo[3];
        p2.x = __float_as_uint(ww[4]); p2.y = oo[4];
        p2.z = __float_as_uint(ww[5]); p2.w = oo[5];
        p3.x = __float_as_uint(ww[6]); p3.y = oo[6];
        p3.z = __float_as_uint(ww[7]); p3.w = oo[7];
        *(uint4*)(wbase + u * 8)           = p0;
        *(uint4*)(wbase + u * 8 + 4)       = p1;
        *(uint4*)(wbase + (u + 8) * 8)     = p2;
        *(uint4*)(wbase + (u + 8) * 8 + 4) = p3;
    }
    __builtin_amdgcn_wave_barrier();   // same-wave producer/consumer only

    // ---- phase 2: coalesced gathers, 4 points per batch ----
    const unsigned int chb = (unsigned int)(u * 8);  // channel byte offset
    const char* vp = (const char*)value;
    float2v acc0; acc0.x = 0.f; acc0.y = 0.f;
    float2v acc1; acc1.x = 0.f; acc1.y = 0.f;

#pragma unroll
    for (int g = 0; g < 4; ++g) {
        const uint4* gp = (const uint4*)(wbase + g * 32);
        uint4 qq[8];
#pragma unroll
        for (int i = 0; i < 8; ++i) qq[i] = gp[i];
        uint2 dB[16];
#pragma unroll
        for (int i = 0; i < 8; ++i) {
            dB[2 * i]     = *(const uint2*)(vp + (qq[i].y + chb));
            dB[2 * i + 1] = *(const uint2*)(vp + (qq[i].w + chb));
        }
#pragma unroll
        for (int i = 0; i < 8; ++i) {
            float2v wa; wa.x = __uint_as_float(qq[i].x); wa.y = wa.x;
            pkfma(acc0, wa, unpk(dB[2 * i].x));
            pkfma(acc1, wa, unpk(dB[2 * i].y));
            float2v wb; wb.x = __uint_as_float(qq[i].z); wb.y = wb.x;
            pkfma(acc0, wb, unpk(dB[2 * i + 1].x));
            pkfma(acc1, wb, unpk(dB[2 * i + 1].y));
        }
    }

    ushort4 r;
    r.x = f2bf(acc0.x); r.y = f2bf(acc0.y);
    r.z = f2bf(acc1.x); r.w = f2bf(acc1.y);
    *(ushort4*)(sb + (long)blk * DMODEL + h * 32 + u * 4) = r;
}

// ---------------------------------------------------------------------------
// out = LayerNorm(out + delta_bf16); writes f32 residual + bf16 outb.
// If qb != null: also writes qb = bf16(LNout + posb) for next layer's q-GEMM.
// ---------------------------------------------------------------------------
__global__ __launch_bounds__(256)
void ln_kernel(float* __restrict__ out, u16* __restrict__ outb,
               u16* __restrict__ qb, const u16* __restrict__ posb,
               const u16* __restrict__ db,
               const float* __restrict__ gamma, const float* __restrict__ beta)
{
    const int wave = threadIdx.x >> 6;
    const int lane = threadIdx.x & 63;
    const long tok = (long)blockIdx.x * 4 + wave;
    float* op = out + tok * DMODEL + lane * 4;
    const float4 xo = *(const float4*)op;
    const ushort4 d4 = *(const ushort4*)(db + tok * DMODEL + lane * 4);
    float x[4] = {xo.x + bf2f(d4.x), xo.y + bf2f(d4.y),
                  xo.z + bf2f(d4.z), xo.w + bf2f(d4.w)};

    float sum = x[0] + x[1] + x[2] + x[3];
#pragma unroll
    for (int o = 32; o >= 1; o >>= 1) sum += __shfl_xor(sum, o);
    const float mean = sum * (1.f / 256.f);

    float vs = 0.f;
#pragma unroll
    for (int i = 0; i < 4; ++i) { const float d2 = x[i] - mean; vs += d2 * d2; }
#pragma unroll
    for (int o = 32; o >= 1; o >>= 1) vs += __shfl_xor(vs, o);
    const float rstd = rsqrtf(vs * (1.f / 256.f) + 1e-5f);

    const float4 g  = *(const float4*)(gamma + lane * 4);
    const float4 be = *(const float4*)(beta + lane * 4);
    float r[4];
    r[0] = (x[0] - mean) * rstd * g.x + be.x;
    r[1] = (x[1] - mean) * rstd * g.y + be.y;
    r[2] = (x[2] - mean) * rstd * g.z + be.z;
    r[3] = (x[3] - mean) * rstd * g.w + be.w;
    float4 rf; rf.x = r[0]; rf.y = r[1]; rf.z = r[2]; rf.w = r[3];
    *(float4*)op = rf;
    ushort4 rb;
    rb.x = f2bf(r[0]); rb.y = f2bf(r[1]); rb.z = f2bf(r[2]); rb.w = f2bf(r[3]);
    *(ushort4*)(outb + tok * DMODEL + lane * 4) = rb;
    if (qb) {
        const ushort4 p4 = *(const ushort4*)(posb + tok * DMODEL + lane * 4);
        ushort4 qv;
        qv.x = f2bf(r[0] + bf2f(p4.x));
        qv.y = f2bf(r[1] + bf2f(p4.y));
        qv.z = f2bf(r[2] + bf2f(p4.z));
        qv.w = f2bf(r[3] + bf2f(p4.w));
        *(ushort4*)(qb + tok * DMODEL + lane * 4) = qv;
    }
}

// ---------------------------------------------------------------------------
extern "C" void kernel_launch(void* const* d_in, const int* in_sizes, int n_in,
                              void* d_out, int out_size, void* d_ws, size_t ws_size,
                              hipStream_t stream)
{
    const float* src[4] = {(const float*)d_in[0], (const float*)d_in[2],
                           (const float*)d_in[4], (const float*)d_in[6]};
    const float* pos[4] = {(const float*)d_in[1], (const float*)d_in[3],
                           (const float*)d_in[5], (const float*)d_in[7]};
    const float* level_embed = (const float*)d_in[8];
    const float* Woff  = (const float*)d_in[9];
    const float* boff  = (const float*)d_in[10];
    const float* Wattn = (const float*)d_in[11];
    const float* battn = (const float*)d_in[12];
    const float* Wval  = (const float*)d_in[13];
    const float* bval  = (const float*)d_in[14];
    const float* Wout  = (const float*)d_in[15];
    const float* bout  = (const float*)d_in[16];
    const float* ln1s  = (const float*)d_in[17];
    const float* ln1b  = (const float*)d_in[18];
    const float* W1    = (const float*)d_in[19];
    const float* b1    = (const float*)d_in[20];
    const float* W2    = (const float*)d_in[21];
    const float* b2    = (const float*)d_in[22];
    const float* ln2s  = (const float*)d_in[23];
    const float* ln2b  = (const float*)d_in[24];

    float* out = (float*)d_out;                       // residual stream f32
    const long MD = (long)MTOT * DMODEL;              // 11,141,120

    // workspace layout (~187 MB)
    u16* outb = (u16*)d_ws;          // [M,256] LN output bf16
    u16* posb = outb + MD;           // [M,256] pos_flat bf16
    u16* qb   = posb + MD;           // [M,256] q = out+pos bf16
    u16* db   = qb + MD;             // [M,256] delta bf16 (attn_out / ff_out)
    u16* vb   = db + MD;             // [M,256] value bf16      (hb region start)
    u16* offb = vb + MD;             // [M,256] offsets bf16
    u16* awb  = offb + MD;           // [M,128] attn logits bf16
    u16* sb   = awb + MD / 2;        // [M,256] sampled bf16
    u16* hb   = vb;                  // [M,1024] FF hidden (aliases vb..sb+pad)
    u16* wts  = vb + 4 * MD;         // bf16 transposed weights
    u16* Wvalt = wts;
    u16* Wofat = Wvalt + 6L * 256 * 256;   // [384,256] per layer: Woff^T||Wattn^T
    u16* Woutt = Wofat + 6L * 384 * 256;
    u16* W1t   = Woutt + 6L * 256 * 256;
    u16* W2t   = W1t   + 6L * 1024 * 256;
    float* bias384 = (float*)(W2t + 6L * 1024 * 256);  // [NLAY][384]

    // ---- weight prep (every call; ~9 MB) ----
    biascat_kernel<<<9, 256, 0, stream>>>(boff, battn, bias384);
    wtrans_kernel<<<dim3(8, 8, 6),  256, 0, stream>>>(Wval,  Wvalt, 256, 256,
                                                      65536, 65536);
    wtrans_kernel<<<dim3(8, 8, 6),  256, 0, stream>>>(Woff,  Wofat, 256, 256,
                                                      65536, 98304);
    wtrans_kernel<<<dim3(4, 8, 6),  256, 0, stream>>>(Wattn, Wofat + 256 * 256,
                                                      256, 128, 32768, 98304);
    wtrans_kernel<<<dim3(8, 8, 6),  256, 0, stream>>>(Wout,  Woutt, 256, 256,
                                                      65536, 65536);
    wtrans_kernel<<<dim3(32, 8, 6), 256, 0, stream>>>(W1,    W1t, 256, 1024,
                                                      262144, 262144);
    wtrans_kernel<<<dim3(8, 32, 6), 256, 0, stream>>>(W2,    W2t, 1024, 256,
                                                      262144, 262144);

    // ---- flatten ----
    {
        const int HW[4] = {16384, 4096, 1024, 256};
        const int ST[4] = {0, 16384, 20480, 21504};
        for (int l = 0; l < 4; ++l) {
            dim3 g(HW[l] / 32, DMODEL / 32, NB);
            flatten_kernel<<<g, 256, 0, stream>>>(src[l], pos[l],
                                                  level_embed + l * DMODEL,
                                                  out, outb, posb, qb, HW[l], ST[l]);
        }
    }

    const dim3 g2(2, MTOT / 128);   // N=256
    const dim3 g3(3, MTOT / 128);   // N=384 (merged off||attn)
    const dim3 g8(8, MTOT / 128);   // N=1024 (FF1)

    for (int i = 0; i < NLAY; ++i) {
        const u16* Wv  = Wvalt + (long)i * 256 * 256;
        const u16* Wqa = Wofat + (long)i * 384 * 256;
        const u16* Wou = Woutt + (long)i * 256 * 256;
        const u16* W1i = W1t   + (long)i * 1024 * 256;
        const u16* W2i = W2t   + (long)i * 256 * 1024;
        const float* bv  = bval + (long)i * 256;
        const float* bqa = bias384 + (long)i * 384;
        const float* bou = bout + (long)i * 256;
        const float* b1i = b1   + (long)i * DFF;
        const float* b2i = b2   + (long)i * 256;

        // value = out @ Wval + bval -> vb bf16
        mfma_gemm<<<g2, 256, 0, stream>>>(outb, Wv, 256, bv,
                                          vb, 256, nullptr, 256, 0);
        // [off | attn logits] = q @ [Woff|Wattn] -> offb bf16, awb bf16
        mfma_gemm<<<g3, 256, 0, stream>>>(qb, Wqa, 256, bqa,
                                          offb, 256, awb, 256, 0);
        // sampling with fused softmax (reads logits directly)
        sample_kernel<<<MTOT / 4, 256, 0, stream>>>(vb, offb, awb, sb);
        // attn_out = s @ Wout + bout -> db bf16
        mfma_gemm<<<g2, 256, 0, stream>>>(sb, Wou, 256, bou,
                                          db, 256, nullptr, 256, 0);
        ln_kernel<<<MTOT / 4, 256, 0, stream>>>(out, outb, nullptr, nullptr, db,
                                                ln1s + (long)i * 256,
                                                ln1b + (long)i * 256);
        // FF: h = relu(out @ W1 + b1) -> hb bf16 [M,1024]
        mfma_gemm<<<g8, 256, 0, stream>>>(outb, W1i, 256, b1i,
                                          hb, 1024, nullptr, 256, 1);
        // ff_out = h @ W2 + b2 -> db bf16
        mfma_gemm<<<g2, 256, 0, stream>>>(hb, W2i, 1024, b2i,
                                          db, 256, nullptr, 1024, 0);
        ln_kernel<<<MTOT / 4, 256, 0, stream>>>(out, outb, qb, posb, db,
                                                ln2s + (long)i * 256,
                                                ln2b + (long)i * 256);
    }
}

// Round 6
// 1860.960 us; speedup vs baseline: 1.1493x; 1.0211x over previous
//
#include <hip/hip_runtime.h>
#include <math.h>

// Problem constants
#define DMODEL 256
#define NHEADS 8
#define NLAY 6
#define DFF 1024
#define DHEAD 32
#define NB 2
#define STOT 21760
#define MTOT (NB * STOT)   // 43520 = 128 * 340

typedef unsigned short u16;
typedef __attribute__((ext_vector_type(8))) short short8;
typedef __attribute__((ext_vector_type(4))) float floatx4;
typedef __attribute__((ext_vector_type(2))) float float2v;

__device__ __forceinline__ float bf2f(u16 h) {
    unsigned int u = ((unsigned int)h) << 16;
    return __uint_as_float(u);
}
__device__ __forceinline__ u16 f2bf(float f) {
    unsigned int u = __float_as_uint(f);
    u = u + 0x7fffu + ((u >> 16) & 1u);   // RNE
    return (u16)(u >> 16);
}

// packed dual-FMA: acc = a * b + acc (2 f32 lanes per instruction)
__device__ __forceinline__ void pkfma(float2v& acc, float2v a, float2v b) {
    asm("v_pk_fma_f32 %0, %1, %2, %0" : "+v"(acc) : "v"(a), "v"(b));
}
// packed bf16 pair (one uint) -> packed f32 pair
__device__ __forceinline__ float2v unpk(unsigned int u) {
    float2v r;
    r.x = __uint_as_float(u << 16);
    r.y = __uint_as_float(u & 0xffff0000u);
    return r;
}

// async global->LDS, 16B per lane. lds dest must be wave-uniform base
// (HW adds lane*16); global src is per-lane.
__device__ __forceinline__ void gload16(const u16* g, u16* l) {
    __builtin_amdgcn_global_load_lds(
        (const __attribute__((address_space(1))) unsigned int*)(g),
        (__attribute__((address_space(3))) unsigned int*)(l),
        16, 0, 0);
}

// ---------------------------------------------------------------------------
// Concatenated bias [NLAY][384] = boff[i] (256) || battn[i] (128)
// ---------------------------------------------------------------------------
__global__ __launch_bounds__(256)
void biascat_kernel(const float* __restrict__ boff, const float* __restrict__ battn,
                    float* __restrict__ bias384)
{
    const int t = blockIdx.x * 256 + threadIdx.x;
    if (t >= NLAY * 384) return;
    const int i = t / 384, c = t - i * 384;
    bias384[t] = (c < 256) ? boff[i * 256 + c] : battn[i * 128 + (c - 256)];
}

// ---------------------------------------------------------------------------
// Weight transpose + bf16 cast: W[K,N] f32 -> Wt[N,K] bf16.
// ---------------------------------------------------------------------------
__global__ __launch_bounds__(256)
void wtrans_kernel(const float* __restrict__ W, u16* __restrict__ Wt,
                   const int K, const int N, const long wstride, const long ostride)
{
    __shared__ float ts[32][33];
    W  += blockIdx.z * wstride;
    Wt += blockIdx.z * ostride;
    const int n0 = blockIdx.x * 32;
    const int k0 = blockIdx.y * 32;
    const int t = threadIdx.x;
    const int nl = t & 31, kl = t >> 5;        // kl 0..7
#pragma unroll
    for (int p = 0; p < 4; ++p) {
        const int k = kl + p * 8;
        ts[k][nl] = W[(long)(k0 + k) * N + n0 + nl];
    }
    __syncthreads();
    const int c = t & 31, r0 = t >> 5;
#pragma unroll
    for (int p = 0; p < 4; ++p) {
        const int r = r0 + p * 8;
        Wt[(long)(n0 + r) * K + k0 + c] = f2bf(ts[c][r]);
    }
}

// ---------------------------------------------------------------------------
// Flatten: src[b,d,y,x] -> out f32, outb bf16, posb bf16, qb = bf16(src+pos+le)
// ---------------------------------------------------------------------------
__global__ __launch_bounds__(256)
void flatten_kernel(const float* __restrict__ src, const float* __restrict__ pos,
                    const float* __restrict__ le_row,
                    float* __restrict__ out, u16* __restrict__ outb,
                    u16* __restrict__ posb, u16* __restrict__ qb,
                    int HW, int start)
{
    __shared__ float ts[32][33];
    __shared__ float tp[32][33];
    const int b   = blockIdx.z;
    const int d0  = blockIdx.y * 32;
    const int hw0 = blockIdx.x * 32;
    const int t   = threadIdx.x;
    const int hwl = t & 31;
    const int dl  = t >> 5;
#pragma unroll
    for (int p = 0; p < 4; ++p) {
        const int dd = dl + p * 8;
        const int d  = d0 + dd;
        const long idx = ((long)(b * DMODEL + d)) * HW + hw0 + hwl;
        ts[dd][hwl] = src[idx];
        tp[dd][hwl] = pos[idx] + le_row[d];
    }
    __syncthreads();
    const int dl2  = t & 31;
    const int hwl2 = t >> 5;
#pragma unroll
    for (int p = 0; p < 4; ++p) {
        const int hh  = hwl2 + p * 8;
        const int tok = start + hw0 + hh;
        const long o  = ((long)(b * STOT + tok)) * DMODEL + d0 + dl2;
        const float v = ts[dl2][hh];
        const float pp = tp[dl2][hh];
        out[o]  = v;
        outb[o] = f2bf(v);
        posb[o] = f2bf(pp);
        qb[o]   = f2bf(v + pp);
    }
}

// ---------------------------------------------------------------------------
// bf16 MFMA GEMM: Cb[M,N]bf16 = A[M,K]bf16 @ Bt[N,K]bf16^T + bias (relu opt)
// Double-buffered global_load_lds pipeline. Optional second problem fused
// along grid.x (block-uniform pointer select): blocks bx >= nsplit compute
// A1 @ Bt1 + bias1 -> Cb1/Cb21 with rebased n0. Shared ldb/ldc/K/relu.
// ---------------------------------------------------------------------------
__global__ __launch_bounds__(256)
void mfma_gemm(const u16* __restrict__ A, const u16* __restrict__ Bt,
               const int ldb, const float* __restrict__ bias,
               u16* __restrict__ Cb, const int ldc, u16* __restrict__ Cb2,
               const int K, const int relu,
               const u16* __restrict__ A1, const u16* __restrict__ Bt1,
               const float* __restrict__ bias1, u16* __restrict__ Cb1,
               u16* __restrict__ Cb21, const int nsplit)
{
    __shared__ u16 As[2][128 * 32];
    __shared__ u16 Bs[2][128 * 32];
    int bx = blockIdx.x;
    if (A1 && bx >= nsplit) {
        A = A1; Bt = Bt1; bias = bias1; Cb = Cb1; Cb2 = Cb21; bx -= nsplit;
    }
    const int tid  = threadIdx.x;
    const int wv   = tid >> 6;
    const int lane = tid & 63;
    const int m0 = blockIdx.y * 128;
    const int n0 = bx * 128;
    const int wm = (wv & 1) * 64;
    const int wn = (wv >> 1) * 64;
    const int q   = lane >> 4;
    const int c16 = lane & 15;

    // staging: chunk = it*4 + wv covers rows [chunk*16, chunk*16+16)
    const int lrow = lane >> 2;
    const int lcol = (lane & 3) * 8;   // u16 units

    const u16* ag[2];
    const u16* bg[2];
#pragma unroll
    for (int it = 0; it < 2; ++it) {
        const int chunk = it * 4 + wv;
        const int row = chunk * 16 + lrow;
        ag[it] = A  + (long)(m0 + row) * K   + lcol;
        bg[it] = Bt + (long)(n0 + row) * ldb + lcol;
    }

#define STAGE(buf, kk)                                          \
    {                                                           \
        _Pragma("unroll")                                       \
        for (int it = 0; it < 2; ++it) {                        \
            const int chunk = it * 4 + wv;                      \
            gload16(ag[it] + (kk), &As[buf][chunk * 512]);      \
            gload16(bg[it] + (kk), &Bs[buf][chunk * 512]);      \
        }                                                       \
    }

    floatx4 acc[4][4];
#pragma unroll
    for (int i = 0; i < 4; ++i)
#pragma unroll
        for (int j = 0; j < 4; ++j)
            acc[i][j] = (floatx4){0.f, 0.f, 0.f, 0.f};

    STAGE(0, 0);
    __syncthreads();

    int cur = 0;
    for (int k0 = 0; k0 < K; k0 += 32) {
        const int nxt = k0 + 32;
        if (nxt < K) {
            if (cur) { STAGE(0, nxt); } else { STAGE(1, nxt); }
        }

        const u16* Ab = &As[cur][0];
        const u16* Bb = &Bs[cur][0];
        short8 af[4], bf[4];
#pragma unroll
        for (int i = 0; i < 4; ++i) {
            af[i] = *(const short8*)&Ab[(wm + i * 16 + c16) * 32 + q * 8];
            bf[i] = *(const short8*)&Bb[(wn + i * 16 + c16) * 32 + q * 8];
        }
#pragma unroll
        for (int i = 0; i < 4; ++i)
#pragma unroll
            for (int j = 0; j < 4; ++j)
                acc[i][j] = __builtin_amdgcn_mfma_f32_16x16x32_bf16(
                    af[i], bf[j], acc[i][j], 0, 0, 0);
        __syncthreads();
        cur ^= 1;
    }
#undef STAGE

    // output selection (block-uniform)
    u16* cb  = Cb;
    int ldcb = ldc, csub = 0;
    if (Cb2 && n0 >= 256) { cb = Cb2; ldcb = 128; csub = 256; }

#pragma unroll
    for (int i = 0; i < 4; ++i) {
#pragma unroll
        for (int j = 0; j < 4; ++j) {
            const int col = n0 + wn + j * 16 + c16;
            const float bv = bias ? bias[col] : 0.f;
#pragma unroll
            for (int r = 0; r < 4; ++r) {
                const int row = m0 + wm + i * 16 + q * 4 + r;
                float v = acc[i][j][r] + bv;
                if (relu) v = fmaxf(v, 0.f);
                cb[(long)row * ldcb + col - csub] = f2bf(v);
            }
        }
    }
}

// ---------------------------------------------------------------------------
// Deformable sampling — hybrid decomposition, LDS-broadcast (w,o) table,
// explicit 2-group-deep gather pipeline (sched_barrier-fenced so the backend
// cannot sink the next group's loads below the current group's FMAs).
// launch_bounds(256,3) allows ~170 VGPR for the double-buffered state.
// ---------------------------------------------------------------------------
__device__ __forceinline__ void point_corners(
    float refx, float refy, unsigned int o2, float aP,
    int k, unsigned int base, float* w, unsigned int* o)
{
    const int lw = 128 >> k;
    const float flw = (float)lw;
    const float x = refx * flw - 0.5f + bf2f((u16)(o2 & 0xffffu));
    const float y = refy * flw - 0.5f + bf2f((u16)(o2 >> 16));
    const float x0f = floorf(x), y0f = floorf(y);
    const float lx = x - x0f, ly = y - y0f;
    const int x0 = (int)x0f, y0 = (int)y0f;
    const float wx0 = ((unsigned int)x0 < (unsigned int)lw) ? (1.f - lx) : 0.f;
    const float wx1 = ((unsigned int)(x0 + 1) < (unsigned int)lw) ? lx : 0.f;
    const float wy0 = ((unsigned int)y0 < (unsigned int)lw) ? (aP * (1.f - ly)) : 0.f;
    const float wy1 = ((unsigned int)(y0 + 1) < (unsigned int)lw) ? (aP * ly) : 0.f;
    // byte offsets: token stride 512B; row stride lw*512 = 1<<(16-k)
    const unsigned int xc0 = (unsigned int)(x0 & (lw - 1)) << 9;
    const unsigned int xc1 = (unsigned int)((x0 + 1) & (lw - 1)) << 9;
    const unsigned int r0 = (unsigned int)(y0 & (lw - 1)) << (16 - k);
    const unsigned int r1 = (unsigned int)((y0 + 1) & (lw - 1)) << (16 - k);
    w[0] = wy0 * wx0; o[0] = base + r0 + xc0;
    w[1] = wy0 * wx1; o[1] = base + r0 + xc1;
    w[2] = wy1 * wx0; o[2] = base + r1 + xc0;
    w[3] = wy1 * wx1; o[3] = base + r1 + xc1;
}

#define LDQ(Q, g)                                                   \
    {                                                               \
        const uint4* gp_ = (const uint4*)(wbase + (g) * 32);        \
        _Pragma("unroll")                                           \
        for (int i = 0; i < 8; ++i) Q[i] = gp_[i];                  \
    }
#define GATH(D, Q)                                                  \
    {                                                               \
        _Pragma("unroll")                                           \
        for (int i = 0; i < 8; ++i) {                               \
            D[2 * i]     = *(const uint2*)(vp + (Q[i].y + chb));    \
            D[2 * i + 1] = *(const uint2*)(vp + (Q[i].w + chb));    \
        }                                                           \
    }
#define FMAG(D, Q)                                                  \
    {                                                               \
        _Pragma("unroll")                                           \
        for (int i = 0; i < 8; ++i) {                               \
            float2v wa; wa.x = __uint_as_float(Q[i].x); wa.y = wa.x;\
            pkfma(acc0, wa, unpk(D[2 * i].x));                      \
            pkfma(acc1, wa, unpk(D[2 * i].y));                      \
            float2v wb; wb.x = __uint_as_float(Q[i].z); wb.y = wb.x;\
            pkfma(acc0, wb, unpk(D[2 * i + 1].x));                  \
            pkfma(acc1, wb, unpk(D[2 * i + 1].y));                  \
        }                                                           \
    }

__global__ __launch_bounds__(256, 3)
void sample_kernel(const u16* __restrict__ value, const u16* __restrict__ offb,
                   const u16* __restrict__ logit, u16* __restrict__ sb)
{
    // per wave: 8 heads x 132 uints (512B payload + 16B pad) = 4224B
    __shared__ unsigned int pwtab[4 * 8 * 132];

    const int t  = threadIdx.x;
    const int wv = t >> 6;                 // token slot within block
    const int l  = t & 63;
    const int h  = l >> 3;                 // head 0..7
    const int u  = l & 7;                  // point-pair owner / channel slice
    const int blk = blockIdx.x * 4 + wv;   // global token
    const int b = blk / STOT;
    const int s = blk - b * STOT;

    float refx, refy;
    if (s < 16384) {
        const int yy = s >> 7, xx = s & 127;
        refx = (xx + 0.5f) * (1.f / 128.f); refy = (yy + 0.5f) * (1.f / 128.f);
    } else if (s < 20480) {
        const int sl = s - 16384; const int yy = sl >> 6, xx = sl & 63;
        refx = (xx + 0.5f) * (1.f / 64.f);  refy = (yy + 0.5f) * (1.f / 64.f);
    } else if (s < 21504) {
        const int sl = s - 20480; const int yy = sl >> 5, xx = sl & 31;
        refx = (xx + 0.5f) * (1.f / 32.f);  refy = (yy + 0.5f) * (1.f / 32.f);
    } else {
        const int sl = s - 21504; const int yy = sl >> 4, xx = sl & 15;
        refx = (xx + 0.5f) * (1.f / 16.f);  refy = (yy + 0.5f) * (1.f / 16.f);
    }

    // ---- phase 1: this lane's 2 points ----
    const unsigned int* offp = (const unsigned int*)(offb + (long)blk * 256 + h * 32);
    const unsigned int o2_0 = offp[u];
    const unsigned int o2_1 = offp[u + 8];
    const u16* lp = logit + (long)blk * 128 + h * 16;
    const float l0 = bf2f(lp[u]);
    const float l1 = bf2f(lp[u + 8]);

    // softmax across the head's 8 lanes (16 logits)
    float m = fmaxf(l0, l1);
    m = fmaxf(m, __shfl_xor(m, 1));
    m = fmaxf(m, __shfl_xor(m, 2));
    m = fmaxf(m, __shfl_xor(m, 4));
    const float e0 = __expf(l0 - m);
    const float e1 = __expf(l1 - m);
    float se = e0 + e1;
    se += __shfl_xor(se, 1);
    se += __shfl_xor(se, 2);
    se += __shfl_xor(se, 4);
    const float inv = 1.f / se;
    const float aP0 = e0 * inv;
    const float aP1 = e1 * inv;

    // levels: point u -> level u>>2 (0/1), point u+8 -> level (u>>2)+2 (2/3)
    const int k0 = u >> 2;
    const unsigned int LS0 = k0 ? 16384u : 0u;
    const unsigned int LS1 = k0 ? 21504u : 20480u;
    const unsigned int tb = (unsigned int)(b * STOT);
    const unsigned int hb64 = (unsigned int)(h * 64);
    const unsigned int base0 = (tb + LS0) * 512u + hb64;
    const unsigned int base1 = (tb + LS1) * 512u + hb64;

    float ww[8];
    unsigned int oo[8];
    point_corners(refx, refy, o2_0, aP0, k0,     base0, ww,     oo);
    point_corners(refx, refy, o2_1, aP1, k0 + 2, base1, ww + 4, oo + 4);

    // ---- publish (w,o) pairs to the per-head LDS table ----
    unsigned int* wbase = pwtab + (wv * 8 + h) * 132;
    {
        uint4 p0, p1, p2, p3;
        p0.x = __float_as_uint(ww[0]); p0.y = oo[0];
        p0.z = __float_as_uint(ww[1]); p0.w = oo[1];
        p1.x = __float_as_uint(ww[2]); p1.y = oo[2];
        p1.z = __float_as_uint(ww[3]); p1.w = oo[3];
        p2.x = __float_as_uint(ww[4]); p2.y = oo[4];
        p2.z = __float_as_uint(ww[5]); p2.w = oo[5];
        p3.x = __float_as_uint(ww[6]); p3.y = oo[6];
        p3.z = __float_as_uint(ww[7]); p3.w = oo[7];
        *(uint4*)(wbase + u * 8)           = p0;
        *(uint4*)(wbase + u * 8 + 4)       = p1;
        *(uint4*)(wbase + (u + 8) * 8)     = p2;
        *(uint4*)(wbase + (u + 8) * 8 + 4) = p3;
    }
    __builtin_amdgcn_wave_barrier();   // same-wave producer/consumer only

    // ---- phase 2: 2-group-deep pipelined gathers ----
    const unsigned int chb = (unsigned int)(u * 8);  // channel byte offset
    const char* vp = (const char*)value;
    float2v acc0; acc0.x = 0.f; acc0.y = 0.f;
    float2v acc1; acc1.x = 0.f; acc1.y = 0.f;

    uint4 qA[8], qB[8];
    uint2 dA[16], dB[16];

    LDQ(qA, 0); GATH(dA, qA);
    LDQ(qB, 1); GATH(dB, qB);
    __builtin_amdgcn_sched_barrier(0);
    FMAG(dA, qA);                       // dB's 16 loads stay in flight
    __builtin_amdgcn_sched_barrier(0);
    LDQ(qA, 2); GATH(dA, qA);
    __builtin_amdgcn_sched_barrier(0);
    FMAG(dB, qB);
    __builtin_amdgcn_sched_barrier(0);
    LDQ(qB, 3); GATH(dB, qB);
    __builtin_amdgcn_sched_barrier(0);
    FMAG(dA, qA);
    __builtin_amdgcn_sched_barrier(0);
    FMAG(dB, qB);

    ushort4 r;
    r.x = f2bf(acc0.x); r.y = f2bf(acc0.y);
    r.z = f2bf(acc1.x); r.w = f2bf(acc1.y);
    *(ushort4*)(sb + (long)blk * DMODEL + h * 32 + u * 4) = r;
}

// ---------------------------------------------------------------------------
// out = LayerNorm(out + delta_bf16); writes f32 residual + bf16 outb.
// If qb != null: also writes qb = bf16(LNout + posb) for next layer's q-GEMM.
// ---------------------------------------------------------------------------
__global__ __launch_bounds__(256)
void ln_kernel(float* __restrict__ out, u16* __restrict__ outb,
               u16* __restrict__ qb, const u16* __restrict__ posb,
               const u16* __restrict__ db,
               const float* __restrict__ gamma, const float* __restrict__ beta)
{
    const int wave = threadIdx.x >> 6;
    const int lane = threadIdx.x & 63;
    const long tok = (long)blockIdx.x * 4 + wave;
    float* op = out + tok * DMODEL + lane * 4;
    const float4 xo = *(const float4*)op;
    const ushort4 d4 = *(const ushort4*)(db + tok * DMODEL + lane * 4);
    float x[4] = {xo.x + bf2f(d4.x), xo.y + bf2f(d4.y),
                  xo.z + bf2f(d4.z), xo.w + bf2f(d4.w)};

    float sum = x[0] + x[1] + x[2] + x[3];
#pragma unroll
    for (int o = 32; o >= 1; o >>= 1) sum += __shfl_xor(sum, o);
    const float mean = sum * (1.f / 256.f);

    float vs = 0.f;
#pragma unroll
    for (int i = 0; i < 4; ++i) { const float d2 = x[i] - mean; vs += d2 * d2; }
#pragma unroll
    for (int o = 32; o >= 1; o >>= 1) vs += __shfl_xor(vs, o);
    const float rstd = rsqrtf(vs * (1.f / 256.f) + 1e-5f);

    const float4 g  = *(const float4*)(gamma + lane * 4);
    const float4 be = *(const float4*)(beta + lane * 4);
    float r[4];
    r[0] = (x[0] - mean) * rstd * g.x + be.x;
    r[1] = (x[1] - mean) * rstd * g.y + be.y;
    r[2] = (x[2] - mean) * rstd * g.z + be.z;
    r[3] = (x[3] - mean) * rstd * g.w + be.w;
    float4 rf; rf.x = r[0]; rf.y = r[1]; rf.z = r[2]; rf.w = r[3];
    *(float4*)op = rf;
    ushort4 rb;
    rb.x = f2bf(r[0]); rb.y = f2bf(r[1]); rb.z = f2bf(r[2]); rb.w = f2bf(r[3]);
    *(ushort4*)(outb + tok * DMODEL + lane * 4) = rb;
    if (qb) {
        const ushort4 p4 = *(const ushort4*)(posb + tok * DMODEL + lane * 4);
        ushort4 qv;
        qv.x = f2bf(r[0] + bf2f(p4.x));
        qv.y = f2bf(r[1] + bf2f(p4.y));
        qv.z = f2bf(r[2] + bf2f(p4.z));
        qv.w = f2bf(r[3] + bf2f(p4.w));
        *(ushort4*)(qb + tok * DMODEL + lane * 4) = qv;
    }
}

// ---------------------------------------------------------------------------
extern "C" void kernel_launch(void* const* d_in, const int* in_sizes, int n_in,
                              void* d_out, int out_size, void* d_ws, size_t ws_size,
                              hipStream_t stream)
{
    const float* src[4] = {(const float*)d_in[0], (const float*)d_in[2],
                           (const float*)d_in[4], (const float*)d_in[6]};
    const float* pos[4] = {(const float*)d_in[1], (const float*)d_in[3],
                           (const float*)d_in[5], (const float*)d_in[7]};
    const float* level_embed = (const float*)d_in[8];
    const float* Woff  = (const float*)d_in[9];
    const float* boff  = (const float*)d_in[10];
    const float* Wattn = (const float*)d_in[11];
    const float* battn = (const float*)d_in[12];
    const float* Wval  = (const float*)d_in[13];
    const float* bval  = (const float*)d_in[14];
    const float* Wout  = (const float*)d_in[15];
    const float* bout  = (const float*)d_in[16];
    const float* ln1s  = (const float*)d_in[17];
    const float* ln1b  = (const float*)d_in[18];
    const float* W1    = (const float*)d_in[19];
    const float* b1    = (const float*)d_in[20];
    const float* W2    = (const float*)d_in[21];
    const float* b2    = (const float*)d_in[22];
    const float* ln2s  = (const float*)d_in[23];
    const float* ln2b  = (const float*)d_in[24];

    float* out = (float*)d_out;                       // residual stream f32
    const long MD = (long)MTOT * DMODEL;              // 11,141,120

    // workspace layout (~187 MB)
    u16* outb = (u16*)d_ws;          // [M,256] LN output bf16
    u16* posb = outb + MD;           // [M,256] pos_flat bf16
    u16* qb   = posb + MD;           // [M,256] q = out+pos bf16
    u16* db   = qb + MD;             // [M,256] delta bf16 (attn_out / ff_out)
    u16* vb   = db + MD;             // [M,256] value bf16      (hb region start)
    u16* offb = vb + MD;             // [M,256] offsets bf16
    u16* awb  = offb + MD;           // [M,128] attn logits bf16
    u16* sb   = awb + MD / 2;        // [M,256] sampled bf16
    u16* hb   = vb;                  // [M,1024] FF hidden (aliases vb..sb+pad)
    u16* wts  = vb + 4 * MD;         // bf16 transposed weights
    u16* Wvalt = wts;
    u16* Wofat = Wvalt + 6L * 256 * 256;   // [384,256] per layer: Woff^T||Wattn^T
    u16* Woutt = Wofat + 6L * 384 * 256;
    u16* W1t   = Woutt + 6L * 256 * 256;
    u16* W2t   = W1t   + 6L * 1024 * 256;
    float* bias384 = (float*)(W2t + 6L * 1024 * 256);  // [NLAY][384]

    // ---- weight prep (every call; ~9 MB) ----
    biascat_kernel<<<9, 256, 0, stream>>>(boff, battn, bias384);
    wtrans_kernel<<<dim3(8, 8, 6),  256, 0, stream>>>(Wval,  Wvalt, 256, 256,
                                                      65536, 65536);
    wtrans_kernel<<<dim3(8, 8, 6),  256, 0, stream>>>(Woff,  Wofat, 256, 256,
                                                      65536, 98304);
    wtrans_kernel<<<dim3(4, 8, 6),  256, 0, stream>>>(Wattn, Wofat + 256 * 256,
                                                      256, 128, 32768, 98304);
    wtrans_kernel<<<dim3(8, 8, 6),  256, 0, stream>>>(Wout,  Woutt, 256, 256,
                                                      65536, 65536);
    wtrans_kernel<<<dim3(32, 8, 6), 256, 0, stream>>>(W1,    W1t, 256, 1024,
                                                      262144, 262144);
    wtrans_kernel<<<dim3(8, 32, 6), 256, 0, stream>>>(W2,    W2t, 1024, 256,
                                                      262144, 262144);

    // ---- flatten ----
    {
        const int HW[4] = {16384, 4096, 1024, 256};
        const int ST[4] = {0, 16384, 20480, 21504};
        for (int l = 0; l < 4; ++l) {
            dim3 g(HW[l] / 32, DMODEL / 32, NB);
            flatten_kernel<<<g, 256, 0, stream>>>(src[l], pos[l],
                                                  level_embed + l * DMODEL,
                                                  out, outb, posb, qb, HW[l], ST[l]);
        }
    }

    const dim3 g2(2, MTOT / 128);   // N=256
    const dim3 g5(5, MTOT / 128);   // merged value (2) + off/attn (3)
    const dim3 g8(8, MTOT / 128);   // N=1024 (FF1)

    for (int i = 0; i < NLAY; ++i) {
        const u16* Wv  = Wvalt + (long)i * 256 * 256;
        const u16* Wqa = Wofat + (long)i * 384 * 256;
        const u16* Wou = Woutt + (long)i * 256 * 256;
        const u16* W1i = W1t   + (long)i * 1024 * 256;
        const u16* W2i = W2t   + (long)i * 256 * 1024;
        const float* bv  = bval + (long)i * 256;
        const float* bqa = bias384 + (long)i * 384;
        const float* bou = bout + (long)i * 256;
        const float* b1i = b1   + (long)i * DFF;
        const float* b2i = b2   + (long)i * 256;

        // merged: value = outb @ Wval + bval -> vb  (blocks 0..1)
        //         [off|attn] = qb @ Wqa + bqa -> offb/awb (blocks 2..4)
        mfma_gemm<<<g5, 256, 0, stream>>>(outb, Wv, 256, bv,
                                          vb, 256, nullptr, 256, 0,
                                          qb, Wqa, bqa, offb, awb, 2);
        // sampling with fused softmax (reads logits directly)
        sample_kernel<<<MTOT / 4, 256, 0, stream>>>(vb, offb, awb, sb);
        // attn_out = s @ Wout + bout -> db bf16
        mfma_gemm<<<g2, 256, 0, stream>>>(sb, Wou, 256, bou,
                                          db, 256, nullptr, 256, 0,
                                          nullptr, nullptr, nullptr, nullptr,
                                          nullptr, 0);
        ln_kernel<<<MTOT / 4, 256, 0, stream>>>(out, outb, nullptr, nullptr, db,
                                                ln1s + (long)i * 256,
                                                ln1b + (long)i * 256);
        // FF: h = relu(out @ W1 + b1) -> hb bf16 [M,1024]
        mfma_gemm<<<g8, 256, 0, stream>>>(outb, W1i, 256, b1i,
                                          hb, 1024, nullptr, 256, 1,
                                          nullptr, nullptr, nullptr, nullptr,
                                          nullptr, 0);
        // ff_out = h @ W2 + b2 -> db bf16
        mfma_gemm<<<g2, 256, 0, stream>>>(hb, W2i, 1024, b2i,
                                          db, 256, nullptr, 1024, 0,
                                          nullptr, nullptr, nullptr, nullptr,
                                          nullptr, 0);
        ln_kernel<<<MTOT / 4, 256, 0, stream>>>(out, outb, qb, posb, db,
                                                ln2s + (long)i * 256,
                                                ln2b + (long)i * 256);
    }
}